// Round 11
// baseline (202.844 us; speedup 1.0000x reference)
//
#include <hip/hip_runtime.h>
#include <math.h>

#define TT 4
#define HH 192
#define WW 192
#define SS 300
#define SP 320              // padded superpixel count (pad masked -inf)
#define HW (HH*WW)
#define PD 3
#define HSZ 22
#define NHP 484             // 22*22 halo pixels
#define NG 1936             // 16B granules per chunk buffer (4 planes x 484)
#define LOG2E 1.44269504088896340736f
#define MOFF 16384          // float index of M table [T][HW]
#define ZOFF (MOFF + TT*HW) // float index of iZ table [T][HW]

typedef _Float16 h8 __attribute__((ext_vector_type(8)));
typedef float f4 __attribute__((ext_vector_type(4)));

// ---------- ws layout (floats) ----------
// [0, 3600)    sums [T][S][3]
// [3600, 4800) cnts [T][S]
// [4800, 9920) means float4 [T][SP]: ((20/ln2)m, w = (-10/ln2)|m|^2 | -inf absent)
// [MOFF ...)   per-pixel max logit M (f32), then iZ = 1/Z (f32)

__global__ void k_zero(float* ws) {
    int i = blockIdx.x * 256 + threadIdx.x;
    if (i < TT * SS * 4) ws[i] = 0.f;
}

// LDS-staged superpixel accumulation: 16 segments x 2304 px per frame
__launch_bounds__(256)
__global__ void k_accum(const float* __restrict__ x, const int* __restrict__ spix,
                        float* __restrict__ ws) {
    __shared__ float ls[SS * 4];
    const int tid = threadIdx.x;
    const int t = blockIdx.y, seg = blockIdx.x;
    for (int i = tid; i < SS * 4; i += 256) ls[i] = 0.f;
    __syncthreads();
#pragma unroll
    for (int it = 0; it < 9; it++) {
        int px = seg * 2304 + it * 256 + tid;
        int s = spix[t * HW + px];
        atomicAdd(&ls[s * 4 + 0], x[(t * 3 + 0) * HW + px]);
        atomicAdd(&ls[s * 4 + 1], x[(t * 3 + 1) * HW + px]);
        atomicAdd(&ls[s * 4 + 2], x[(t * 3 + 2) * HW + px]);
        atomicAdd(&ls[s * 4 + 3], 1.f);
    }
    __syncthreads();
    for (int i = tid; i < SS * 4; i += 256) {
        float v = ls[i];
        if (v != 0.f) {
            int s = i >> 2, c = i & 3;
            if (c < 3) atomicAdd(&ws[(t * SS + s) * 3 + c], v);
            else       atomicAdd(&ws[3600 + t * SS + s], v);
        }
    }
}

__global__ void k_means(float* __restrict__ ws) {
    int i = blockIdx.x * 256 + threadIdx.x;
    if (i >= TT * SP) return;
    int t = i / SP, s = i - t * SP;
    const float* sums = ws;
    const float* cnts = ws + TT * SS * 3;
    float4* m4 = (float4*)(ws + 4800);
    float4 m;
    if (s < SS) {
        float c = cnts[t * SS + s];
        float inv = 1.f / fmaxf(c, 1.f);
        float mx = sums[(t * SS + s) * 3 + 0] * inv;
        float my = sums[(t * SS + s) * 3 + 1] * inv;
        float mz = sums[(t * SS + s) * 3 + 2] * inv;
        m.x = 20.f * LOG2E * mx; m.y = 20.f * LOG2E * my; m.z = 20.f * LOG2E * mz;
        m.w = (c > 0.f) ? (-10.f * LOG2E * (mx * mx + my * my + mz * mz)) : -INFINITY;
    } else {
        m.x = 0.f; m.y = 0.f; m.z = 0.f; m.w = -INFINITY;
    }
    m4[t * SP + s] = m;
}

// ---- per-pixel max logit M and iZ, 2 px/thread ----
__launch_bounds__(256)
__global__ void k_prep(const float* __restrict__ x, float* __restrict__ ws) {
    __shared__ float4 sm[SP];
    const int tid = threadIdx.x;
    const int t = blockIdx.y;
    const int p0 = blockIdx.x * 512 + tid;
    const int p1 = p0 + 256;
    const float4* m4 = (const float4*)(ws + 4800) + t * SP;
    for (int i = tid; i < SP; i += 256) sm[i] = m4[i];
    __syncthreads();
    const float f0x = x[(t * 3 + 0) * HW + p0], f0y = x[(t * 3 + 1) * HW + p0], f0z = x[(t * 3 + 2) * HW + p0];
    const float f1x = x[(t * 3 + 0) * HW + p1], f1y = x[(t * 3 + 1) * HW + p1], f1z = x[(t * 3 + 2) * HW + p1];

    float M0 = -INFINITY, M1 = -INFINITY;
#pragma unroll 4
    for (int s = 0; s < SP; s++) {
        float4 a = sm[s];
        M0 = fmaxf(M0, fmaf(f0x, a.x, fmaf(f0y, a.y, fmaf(f0z, a.z, a.w))));
        M1 = fmaxf(M1, fmaf(f1x, a.x, fmaf(f1y, a.y, fmaf(f1z, a.z, a.w))));
    }
    float Z0 = 0.f, Z1 = 0.f;
#pragma unroll 4
    for (int s = 0; s < SP; s++) {
        float4 a = sm[s];
        Z0 += exp2f(fmaf(f0x, a.x, fmaf(f0y, a.y, fmaf(f0z, a.z, a.w))) - M0);
        Z1 += exp2f(fmaf(f1x, a.x, fmaf(f1y, a.y, fmaf(f1z, a.z, a.w))) - M1);
    }
    ws[MOFF + t * HW + p0] = M0;
    ws[MOFF + t * HW + p1] = M1;
    ws[ZOFF + t * HW + p0] = 1.f / Z0;
    ws[ZOFF + t * HW + p1] = 1.f / Z1;
}

#define REP49(M) M(0)M(1)M(2)M(3)M(4)M(5)M(6)M(7)M(8)M(9)M(10)M(11)M(12)M(13) \
    M(14)M(15)M(16)M(17)M(18)M(19)M(20)M(21)M(22)M(23)M(24)M(25)M(26)M(27) \
    M(28)M(29)M(30)M(31)M(32)M(33)M(34)M(35)M(36)M(37)M(38)M(39)M(40)M(41) \
    M(42)M(43)M(44)M(45)M(46)M(47)M(48)

#define QOFF(k) (((k) / 7 - PD) * HSZ + ((k) % 7 - PD))

// ================= fused: E (in-LDS) + MFMA attn + norm + linear =================
// 16x16 tile, 1024 threads (16 waves), 1 p-row per wave -> 14 f4 accs (56 regs).
// E chunk = 32 s (4 planes of 8) in LDS, plane-major granules (jd*484+px),
// double-buffered. phaseB: 2 threads per halo px (16 s each).
// attn gathered via f32 LDS overlay (stride 51) aliasing ebuf; epilogue 1 thread/px.
// launch_bounds(1024,1): >=128 VGPR cap under either arg-2 semantics (r10 lesson:
// (1024,4) forced a 64-VGPR cap -> full accumulator spill).

__launch_bounds__(1024, 1)
__global__ void k_main(const float* __restrict__ x, const float* __restrict__ Wlin,
                       const float* __restrict__ blin, const float* __restrict__ ws,
                       float* __restrict__ out) {
    __shared__ __align__(16) char ebuf[2][NG * 16];   // 61952 B (attn overlay reuses this)
    __shared__ float4 sfh[NHP];                       // xyz = feature, w = iZ (0 if OOB)
    __shared__ float  sW[441];

    const int tid = threadIdx.x;
    const int wid = tid >> 6, lane = tid & 63;
    const int pxc = lane & 15, kg = lane >> 4;        // MFMA fragment coords
    const int t = blockIdx.z;
    const int gx0 = blockIdx.x * 16 - PD, gy0 = blockIdx.y * 16 - PD;
    const float4* m4 = (const float4*)(ws + 4800) + t * SP;

    for (int i = tid; i < 441; i += 1024) sW[i] = Wlin[i];

    // ---- per-thread halo-pixel state: threads 0..483 = half 0 (jd 0,1),
    //      484..967 = half 1 (jd 2,3); same hp in both halves ----
    const int half = (tid >= NHP) ? 1 : 0;
    const int hp = tid - half * NHP;
    float fx = 0.f, fy = 0.f, fz = 0.f, M = INFINITY;
    if (tid < 2 * NHP) {
        int hy = hp / HSZ, hx = hp - hy * HSZ;
        int gy = gy0 + hy, gx = gx0 + hx;
        if (gy >= 0 && gy < HH && gx >= 0 && gx < WW) {
            int p = gy * WW + gx;
            fx = x[(t * 3 + 0) * HW + p];
            fy = x[(t * 3 + 1) * HW + p];
            fz = x[(t * 3 + 2) * HW + p];
            M  = ws[MOFF + t * HW + p];
            if (half == 0) sfh[hp] = make_float4(fx, fy, fz, ws[ZOFF + t * HW + p]);
        } else if (half == 0) {
            sfh[hp] = make_float4(0.f, 0.f, 0.f, 0.f);
        }
    }

    // phase B: E values for chunk cc -> buffer bb (OOB px: M=+inf -> E=0)
#define PHASEB(cc, bb) if (tid < 2 * NHP) { \
        char* dst = ebuf[bb]; \
        _Pragma("unroll") \
        for (int j2 = 0; j2 < 2; j2++) { \
            int jd = 2 * half + j2; \
            h8 v; \
            _Pragma("unroll") \
            for (int e = 0; e < 4; e++) { \
                float4 ma = m4[(cc) * 32 + jd * 8 + 2 * e]; \
                float4 mb = m4[(cc) * 32 + jd * 8 + 2 * e + 1]; \
                float E0 = exp2f(fmaf(fx, ma.x, fmaf(fy, ma.y, fmaf(fz, ma.z, ma.w))) - M); \
                float E1 = exp2f(fmaf(fx, mb.x, fmaf(fy, mb.y, fmaf(fz, mb.z, mb.w))) - M); \
                auto pr = __builtin_amdgcn_cvt_pkrtz(E0, E1); \
                v[2 * e] = (_Float16)pr.x; v[2 * e + 1] = (_Float16)pr.y; \
            } \
            *(h8*)(dst + (jd * NHP + hp) * 16) = v; \
        } }

    // ---- MFMA setup: wave owns p-row r = wid ----
    const int r = wid;
    const int gA0 = kg * NHP + (r + PD) * HSZ + PD + pxc;           // A row r
    const int bcol2 = (16 + pxc > 21) ? 21 : 16 + pxc;              // clamped tile2 col
    const int gB1 = kg * NHP + r * HSZ + pxc;                       // + d*HSZ
    const int gB2 = kg * NHP + r * HSZ + bcol2;                     // + d*HSZ

    f4 zero4 = {0.f, 0.f, 0.f, 0.f};
    f4 aP[7], aQ[7];                 // (A,B1[d]) (A,B2[d])
#pragma unroll
    for (int d = 0; d < 7; d++) { aP[d] = zero4; aQ[d] = zero4; }

    PHASEB(0, 0)

#pragma unroll 1
    for (int c = 0; c < 10; c++) {
        __syncthreads();               // phaseB(c) visible; MFMA(c-1) reads done
        if (c < 9) { PHASEB(c + 1, (c + 1) & 1) }
        const char* pb = ebuf[c & 1];
        h8 A0 = *(const h8*)(pb + gA0 * 16);
#pragma unroll
        for (int d = 0; d < 7; d++) {
            h8 n1 = *(const h8*)(pb + (gB1 + d * HSZ) * 16);
            h8 n2 = *(const h8*)(pb + (gB2 + d * HSZ) * 16);
            aP[d] = __builtin_amdgcn_mfma_f32_16x16x32_f16(A0, n1, aP[d], 0, 0, 0);
            aQ[d] = __builtin_amdgcn_mfma_f32_16x16x32_f16(A0, n2, aQ[d], 0, 0, 0);
        }
    }
    __syncthreads();                   // last MFMA reads done; ebuf reusable

    // ---- band write-out: D[i = 4*kg+reg, j = pxc] -> attn[px][k] (each slot once) ----
    float* attn = (float*)ebuf;        // [256 px][stride 51] f32, 52.2 KB < 62 KB
#pragma unroll
    for (int d = 0; d < 7; d++) {
#pragma unroll
        for (int reg = 0; reg < 4; reg++) {
            int i = 4 * kg + reg;
            int u1 = pxc - i;          // tile1: dx+3 = j-i
            int u2 = u1 + 16;          // tile2: dx+3 = 16+j-i
            if ((unsigned)u1 <= 6u) attn[(r * 16 + i) * 51 + d * 7 + u1] = aP[d][reg];
            if ((unsigned)u2 <= 6u) attn[(r * 16 + i) * 51 + d * 7 + u2] = aQ[d][reg];
        }
    }
    __syncthreads();

    // ---- normalize (eps+max semantics) + linear epilogue (1 thread / pixel) ----
    if (tid < 256) {
        const int rr = tid >> 4, cq = tid & 15;
        const int own = (rr + PD) * HSZ + (cq + PD);
        const float* ap = attn + tid * 51;
        float mx = 0.f;
#define PK1(k) mx = fmaxf(mx, ap[k] * sfh[own + QOFF(k)].w);
        REP49(PK1)
#undef PK1
        const float iZp = sfh[own].w;
        const float inv = 1.f / (1e-5f / iZp + mx);

        float o0 = blin[0], o1 = blin[1], o2 = blin[2];
#define PK2(k) { float4 f = sfh[own + QOFF(k)]; \
        float rwk = ap[k] * f.w * inv; \
        o0 += rwk * (sW[k] * f.x + sW[49 + (k)] * f.y + sW[98 + (k)] * f.z); \
        o1 += rwk * (sW[147 + (k)] * f.x + sW[196 + (k)] * f.y + sW[245 + (k)] * f.z); \
        o2 += rwk * (sW[294 + (k)] * f.x + sW[343 + (k)] * f.y + sW[392 + (k)] * f.z); }
        REP49(PK2)
#undef PK2

        int p = (gy0 + PD + rr) * WW + gx0 + PD + cq;
        out[(t * 3 + 0) * HW + p] = o0;
        out[(t * 3 + 1) * HW + p] = o1;
        out[(t * 3 + 2) * HW + p] = o2;
    }
}

extern "C" void kernel_launch(void* const* d_in, const int* in_sizes, int n_in,
                              void* d_out, int out_size, void* d_ws, size_t ws_size,
                              hipStream_t stream) {
    (void)in_sizes; (void)n_in; (void)out_size; (void)ws_size;
    const float* x    = (const float*)d_in[0];
    const int*   spix = (const int*)d_in[1];
    const float* Wlin = (const float*)d_in[2];
    const float* blin = (const float*)d_in[3];
    float* out = (float*)d_out;
    float* ws  = (float*)d_ws;

    hipLaunchKernelGGL(k_zero,  dim3(19), dim3(256), 0, stream, ws);
    hipLaunchKernelGGL(k_accum, dim3(16, TT), dim3(256), 0, stream, x, spix, ws);
    hipLaunchKernelGGL(k_means, dim3((TT * SP + 255) / 256), dim3(256), 0, stream, ws);
    hipLaunchKernelGGL(k_prep,  dim3(HW / 512, TT), dim3(256), 0, stream, x, ws);
    hipLaunchKernelGGL(k_main,  dim3(WW / 16, HH / 16, TT), dim3(1024), 0, stream,
                       x, Wlin, blin, ws, out);
}

// Round 12
// 143.086 us; speedup vs baseline: 1.4176x; 1.4176x over previous
//
#include <hip/hip_runtime.h>
#include <math.h>

#define TT 4
#define HH 192
#define WW 192
#define SS 300
#define SP 320              // padded superpixel count (pad masked -inf)
#define HW (HH*WW)
#define PD 3
#define HSZ 22
#define NHP 484             // 22*22 halo pixels
#define NG 1936             // 16B granules per chunk buffer (4 planes x 484)
#define LOG2E 1.44269504088896340736f
#define MOFF 16384          // float index of M table [T][HW]
#define ZOFF (MOFF + TT*HW) // float index of iZ table [T][HW]

typedef _Float16 h8 __attribute__((ext_vector_type(8)));
typedef float f4 __attribute__((ext_vector_type(4)));

// ---------- ws layout (floats) ----------
// [0, 3600)    sums [T][S][3]
// [3600, 4800) cnts [T][S]
// [4800, 9920) means float4 [T][SP]: ((20/ln2)m, w = (-10/ln2)|m|^2 | -inf absent)
// [MOFF ...)   per-pixel max logit M (f32), then iZ = 1/Z (f32)

__global__ void k_zero(float* ws) {
    int i = blockIdx.x * 256 + threadIdx.x;
    if (i < TT * SS * 4) ws[i] = 0.f;
}

// LDS-staged superpixel accumulation: 16 segments x 2304 px per frame
__launch_bounds__(256)
__global__ void k_accum(const float* __restrict__ x, const int* __restrict__ spix,
                        float* __restrict__ ws) {
    __shared__ float ls[SS * 4];
    const int tid = threadIdx.x;
    const int t = blockIdx.y, seg = blockIdx.x;
    for (int i = tid; i < SS * 4; i += 256) ls[i] = 0.f;
    __syncthreads();
#pragma unroll
    for (int it = 0; it < 9; it++) {
        int px = seg * 2304 + it * 256 + tid;
        int s = spix[t * HW + px];
        atomicAdd(&ls[s * 4 + 0], x[(t * 3 + 0) * HW + px]);
        atomicAdd(&ls[s * 4 + 1], x[(t * 3 + 1) * HW + px]);
        atomicAdd(&ls[s * 4 + 2], x[(t * 3 + 2) * HW + px]);
        atomicAdd(&ls[s * 4 + 3], 1.f);
    }
    __syncthreads();
    for (int i = tid; i < SS * 4; i += 256) {
        float v = ls[i];
        if (v != 0.f) {
            int s = i >> 2, c = i & 3;
            if (c < 3) atomicAdd(&ws[(t * SS + s) * 3 + c], v);
            else       atomicAdd(&ws[3600 + t * SS + s], v);
        }
    }
}

__global__ void k_means(float* __restrict__ ws) {
    int i = blockIdx.x * 256 + threadIdx.x;
    if (i >= TT * SP) return;
    int t = i / SP, s = i - t * SP;
    const float* sums = ws;
    const float* cnts = ws + TT * SS * 3;
    float4* m4 = (float4*)(ws + 4800);
    float4 m;
    if (s < SS) {
        float c = cnts[t * SS + s];
        float inv = 1.f / fmaxf(c, 1.f);
        float mx = sums[(t * SS + s) * 3 + 0] * inv;
        float my = sums[(t * SS + s) * 3 + 1] * inv;
        float mz = sums[(t * SS + s) * 3 + 2] * inv;
        m.x = 20.f * LOG2E * mx; m.y = 20.f * LOG2E * my; m.z = 20.f * LOG2E * mz;
        m.w = (c > 0.f) ? (-10.f * LOG2E * (mx * mx + my * my + mz * mz)) : -INFINITY;
    } else {
        m.x = 0.f; m.y = 0.f; m.z = 0.f; m.w = -INFINITY;
    }
    m4[t * SP + s] = m;
}

// ---- per-pixel max logit M and iZ, 2 px/thread ----
__launch_bounds__(256)
__global__ void k_prep(const float* __restrict__ x, float* __restrict__ ws) {
    __shared__ float4 sm[SP];
    const int tid = threadIdx.x;
    const int t = blockIdx.y;
    const int p0 = blockIdx.x * 512 + tid;
    const int p1 = p0 + 256;
    const float4* m4 = (const float4*)(ws + 4800) + t * SP;
    for (int i = tid; i < SP; i += 256) sm[i] = m4[i];
    __syncthreads();
    const float f0x = x[(t * 3 + 0) * HW + p0], f0y = x[(t * 3 + 1) * HW + p0], f0z = x[(t * 3 + 2) * HW + p0];
    const float f1x = x[(t * 3 + 0) * HW + p1], f1y = x[(t * 3 + 1) * HW + p1], f1z = x[(t * 3 + 2) * HW + p1];

    float M0 = -INFINITY, M1 = -INFINITY;
#pragma unroll 4
    for (int s = 0; s < SP; s++) {
        float4 a = sm[s];
        M0 = fmaxf(M0, fmaf(f0x, a.x, fmaf(f0y, a.y, fmaf(f0z, a.z, a.w))));
        M1 = fmaxf(M1, fmaf(f1x, a.x, fmaf(f1y, a.y, fmaf(f1z, a.z, a.w))));
    }
    float Z0 = 0.f, Z1 = 0.f;
#pragma unroll 4
    for (int s = 0; s < SP; s++) {
        float4 a = sm[s];
        Z0 += exp2f(fmaf(f0x, a.x, fmaf(f0y, a.y, fmaf(f0z, a.z, a.w))) - M0);
        Z1 += exp2f(fmaf(f1x, a.x, fmaf(f1y, a.y, fmaf(f1z, a.z, a.w))) - M1);
    }
    ws[MOFF + t * HW + p0] = M0;
    ws[MOFF + t * HW + p1] = M1;
    ws[ZOFF + t * HW + p0] = 1.f / Z0;
    ws[ZOFF + t * HW + p1] = 1.f / Z1;
}

#define REP49(M) M(0)M(1)M(2)M(3)M(4)M(5)M(6)M(7)M(8)M(9)M(10)M(11)M(12)M(13) \
    M(14)M(15)M(16)M(17)M(18)M(19)M(20)M(21)M(22)M(23)M(24)M(25)M(26)M(27) \
    M(28)M(29)M(30)M(31)M(32)M(33)M(34)M(35)M(36)M(37)M(38)M(39)M(40)M(41) \
    M(42)M(43)M(44)M(45)M(46)M(47)M(48)

#define QOFF(k) (((k) / 7 - PD) * HSZ + ((k) % 7 - PD))

// ================= fused: E (in-LDS) + MFMA attn + norm + linear =================
// Round-9 structure (512 threads, (512,2): 124 VGPR no-spill, 2 blocks/CU) +
// means staged in LDS (5KB): phase B reads are wave-uniform LDS broadcasts
// instead of per-chunk global loads (the suspected lockstep stall).

__launch_bounds__(512, 2)
__global__ void k_main(const float* __restrict__ x, const float* __restrict__ Wlin,
                       const float* __restrict__ blin, const float* __restrict__ ws,
                       float* __restrict__ out) {
    __shared__ __align__(16) char ebuf[2][NG * 16];   // 61952 B (attn overlay reuses this)
    __shared__ float4 sfh[NHP];                       // xyz = feature, w = iZ (0 if OOB)
    __shared__ float  sW[441];
    __shared__ float4 smean[SP];                      // 5120 B

    const int tid = threadIdx.x;
    const int wid = tid >> 6, lane = tid & 63;
    const int pxc = lane & 15, kg = lane >> 4;        // MFMA fragment coords
    const int t = blockIdx.z;
    const int gx0 = blockIdx.x * 16 - PD, gy0 = blockIdx.y * 16 - PD;
    const float4* m4 = (const float4*)(ws + 4800) + t * SP;

    for (int i = tid; i < 441; i += 512) sW[i] = Wlin[i];
    for (int i = tid; i < SP; i += 512) smean[i] = m4[i];

    // ---- per-halo-pixel state (loads only; M/iZ precomputed) ----
    float fx = 0.f, fy = 0.f, fz = 0.f, M = INFINITY;
    if (tid < NHP) {
        int hy = tid / HSZ, hx = tid - hy * HSZ;
        int gy = gy0 + hy, gx = gx0 + hx;
        float iZ = 0.f;
        if (gy >= 0 && gy < HH && gx >= 0 && gx < WW) {
            int p = gy * WW + gx;
            fx = x[(t * 3 + 0) * HW + p];
            fy = x[(t * 3 + 1) * HW + p];
            fz = x[(t * 3 + 2) * HW + p];
            M  = ws[MOFF + t * HW + p];
            iZ = ws[ZOFF + t * HW + p];
        }
        sfh[tid] = make_float4(fx, fy, fz, iZ);
    }
    __syncthreads();   // smean (and sfh/sW) visible before PHASEB(0)

    // phase B: E values for chunk cc -> buffer bb (OOB px: M=+inf -> E=0)
#define PHASEB(cc, bb) if (tid < NHP) { \
        char* dst = ebuf[bb]; \
        _Pragma("unroll") \
        for (int jd = 0; jd < 4; jd++) { \
            h8 v; \
            _Pragma("unroll") \
            for (int e = 0; e < 4; e++) { \
                float4 ma = smean[(cc) * 32 + jd * 8 + 2 * e]; \
                float4 mb = smean[(cc) * 32 + jd * 8 + 2 * e + 1]; \
                float E0 = exp2f(fmaf(fx, ma.x, fmaf(fy, ma.y, fmaf(fz, ma.z, ma.w))) - M); \
                float E1 = exp2f(fmaf(fx, mb.x, fmaf(fy, mb.y, fmaf(fz, mb.z, mb.w))) - M); \
                auto pr = __builtin_amdgcn_cvt_pkrtz(E0, E1); \
                v[2 * e] = (_Float16)pr.x; v[2 * e + 1] = (_Float16)pr.y; \
            } \
            *(h8*)(dst + (jd * NHP + tid) * 16) = v; \
        } }

    // ---- MFMA setup: wave owns rows r0, r0+1 of the 16x16 tile ----
    const int r0 = 2 * wid;
    const int gA0 = kg * NHP + (r0 + PD) * HSZ + PD + pxc;          // A row r0
    const int gA1 = gA0 + HSZ;                                      // A row r0+1
    const int bcol2 = (16 + pxc > 21) ? 21 : 16 + pxc;              // clamped tile2 col
    const int gB1 = kg * NHP + r0 * HSZ + pxc;                      // + d*HSZ
    const int gB2 = kg * NHP + r0 * HSZ + bcol2;                    // + d*HSZ

    f4 zero4 = {0.f, 0.f, 0.f, 0.f};
    f4 aP[7], aQ[7], aR[7], aS[7];   // (A0,B1[d]) (A0,B2[d]) (A1,B1[d+1]) (A1,B2[d+1])
#pragma unroll
    for (int d = 0; d < 7; d++) { aP[d] = zero4; aQ[d] = zero4; aR[d] = zero4; aS[d] = zero4; }

    PHASEB(0, 0)

#pragma unroll 1
    for (int c = 0; c < 10; c++) {
        __syncthreads();               // phaseB(c) visible; MFMA(c-1) reads done
        if (c < 9) { PHASEB(c + 1, (c + 1) & 1) }
        const char* pb = ebuf[c & 1];
        h8 A0 = *(const h8*)(pb + gA0 * 16);
        h8 A1 = *(const h8*)(pb + gA1 * 16);
        // d = 0: B[0] feeds row r0 only
        h8 b1 = *(const h8*)(pb + gB1 * 16);
        h8 b2 = *(const h8*)(pb + gB2 * 16);
        aP[0] = __builtin_amdgcn_mfma_f32_16x16x32_f16(A0, b1, aP[0], 0, 0, 0);
        aQ[0] = __builtin_amdgcn_mfma_f32_16x16x32_f16(A0, b2, aQ[0], 0, 0, 0);
#pragma unroll
        for (int d = 1; d < 7; d++) {  // B[d] feeds row r0 (as d) and row r0+1 (as d-1)
            h8 n1 = *(const h8*)(pb + (gB1 + d * HSZ) * 16);
            h8 n2 = *(const h8*)(pb + (gB2 + d * HSZ) * 16);
            aP[d]     = __builtin_amdgcn_mfma_f32_16x16x32_f16(A0, n1, aP[d], 0, 0, 0);
            aR[d - 1] = __builtin_amdgcn_mfma_f32_16x16x32_f16(A1, n1, aR[d - 1], 0, 0, 0);
            aQ[d]     = __builtin_amdgcn_mfma_f32_16x16x32_f16(A0, n2, aQ[d], 0, 0, 0);
            aS[d - 1] = __builtin_amdgcn_mfma_f32_16x16x32_f16(A1, n2, aS[d - 1], 0, 0, 0);
        }
        // d = 7: B[7] feeds row r0+1 only
        h8 l1 = *(const h8*)(pb + (gB1 + 7 * HSZ) * 16);
        h8 l2 = *(const h8*)(pb + (gB2 + 7 * HSZ) * 16);
        aR[6] = __builtin_amdgcn_mfma_f32_16x16x32_f16(A1, l1, aR[6], 0, 0, 0);
        aS[6] = __builtin_amdgcn_mfma_f32_16x16x32_f16(A1, l2, aS[6], 0, 0, 0);
    }
    __syncthreads();                   // last MFMA reads done; ebuf reusable

    // ---- band write-out: D[i = 4*kg+reg, j = pxc] -> attn[px][k] (each slot once) ----
    float* attn = (float*)ebuf;        // [256 px][stride 51] f32, 52.2 KB < 62 KB
#pragma unroll
    for (int d = 0; d < 7; d++) {
#pragma unroll
        for (int reg = 0; reg < 4; reg++) {
            int i = 4 * kg + reg;
            int u1 = pxc - i;          // tile1: dx+3 = j-i
            int u2 = u1 + 16;          // tile2: dx+3 = 16+j-i
            if ((unsigned)u1 <= 6u) {
                attn[(r0 * 16 + i) * 51 + d * 7 + u1] = aP[d][reg];
                attn[((r0 + 1) * 16 + i) * 51 + d * 7 + u1] = aR[d][reg];
            }
            if ((unsigned)u2 <= 6u) {
                attn[(r0 * 16 + i) * 51 + d * 7 + u2] = aQ[d][reg];
                attn[((r0 + 1) * 16 + i) * 51 + d * 7 + u2] = aS[d][reg];
            }
        }
    }
    __syncthreads();

    // ---- normalize (eps+max semantics) + linear epilogue (1 thread / pixel) ----
    if (tid < 256) {
        const int r = tid >> 4, cq = tid & 15;
        const int own = (r + PD) * HSZ + (cq + PD);
        const float* ap = attn + tid * 51;
        float mx = 0.f;
#define PK1(k) mx = fmaxf(mx, ap[k] * sfh[own + QOFF(k)].w);
        REP49(PK1)
#undef PK1
        const float iZp = sfh[own].w;
        const float inv = 1.f / (1e-5f / iZp + mx);

        float o0 = blin[0], o1 = blin[1], o2 = blin[2];
#define PK2(k) { float4 f = sfh[own + QOFF(k)]; \
        float rwk = ap[k] * f.w * inv; \
        o0 += rwk * (sW[k] * f.x + sW[49 + (k)] * f.y + sW[98 + (k)] * f.z); \
        o1 += rwk * (sW[147 + (k)] * f.x + sW[196 + (k)] * f.y + sW[245 + (k)] * f.z); \
        o2 += rwk * (sW[294 + (k)] * f.x + sW[343 + (k)] * f.y + sW[392 + (k)] * f.z); }
        REP49(PK2)
#undef PK2

        int p = (gy0 + PD + r) * WW + gx0 + PD + cq;
        out[(t * 3 + 0) * HW + p] = o0;
        out[(t * 3 + 1) * HW + p] = o1;
        out[(t * 3 + 2) * HW + p] = o2;
    }
}

extern "C" void kernel_launch(void* const* d_in, const int* in_sizes, int n_in,
                              void* d_out, int out_size, void* d_ws, size_t ws_size,
                              hipStream_t stream) {
    (void)in_sizes; (void)n_in; (void)out_size; (void)ws_size;
    const float* x    = (const float*)d_in[0];
    const int*   spix = (const int*)d_in[1];
    const float* Wlin = (const float*)d_in[2];
    const float* blin = (const float*)d_in[3];
    float* out = (float*)d_out;
    float* ws  = (float*)d_ws;

    hipLaunchKernelGGL(k_zero,  dim3(19), dim3(256), 0, stream, ws);
    hipLaunchKernelGGL(k_accum, dim3(16, TT), dim3(256), 0, stream, x, spix, ws);
    hipLaunchKernelGGL(k_means, dim3((TT * SP + 255) / 256), dim3(256), 0, stream, ws);
    hipLaunchKernelGGL(k_prep,  dim3(HW / 512, TT), dim3(256), 0, stream, x, ws);
    hipLaunchKernelGGL(k_main,  dim3(WW / 16, HH / 16, TT), dim3(512), 0, stream,
                       x, Wlin, blin, ws, out);
}

// Round 13
// 135.888 us; speedup vs baseline: 1.4927x; 1.0530x over previous
//
#include <hip/hip_runtime.h>
#include <math.h>

#define TT 4
#define HH 192
#define WW 192
#define SS 300
#define SP 320              // padded superpixel count (pad masked -inf)
#define HW (HH*WW)
#define PD 3
#define HSZ 22
#define NHP 484             // 22*22 halo pixels
#define NG 1936             // 16B granules per chunk buffer (4 planes x 484)
#define LOG2E 1.44269504088896340736f
#define MEANS 81920         // float index of means float4 [T][SP]
#define MOFF 98304          // float index of M table [T][HW]
#define ZOFF (MOFF + TT*HW) // float index of iZ table [T][HW]

typedef _Float16 h8 __attribute__((ext_vector_type(8)));
typedef float f4 __attribute__((ext_vector_type(4)));

// ---------- ws layout (floats) ----------
// [0, 76800)       partial sums [T][16 seg][300 s][4: sx,sy,sz,cnt]
// [MEANS, +5120)   means float4 [T][SP]: ((20/ln2)m, w = (-10/ln2)|m|^2 | -inf absent)
// [MOFF ...)       per-pixel max logit M (f32), then iZ = 1/Z (f32)

// per-segment partial sums: no zeroed global table, no global atomics.
// thread owns 9 CONSECUTIVE px -> same-superpixel runs combined in registers.
__launch_bounds__(256)
__global__ void k_accum(const float* __restrict__ x, const int* __restrict__ spix,
                        float* __restrict__ ws) {
    __shared__ float ls[SS * 4];
    const int tid = threadIdx.x;
    const int t = blockIdx.y, seg = blockIdx.x;
    for (int i = tid; i < SS * 4; i += 256) ls[i] = 0.f;
    __syncthreads();
    const int pb = seg * 2304 + tid * 9;
    const int* sp = spix + t * HW + pb;
    const float* x0 = x + (t * 3 + 0) * HW + pb;
    const float* x1 = x + (t * 3 + 1) * HW + pb;
    const float* x2 = x + (t * 3 + 2) * HW + pb;
    float a0 = 0.f, a1 = 0.f, a2 = 0.f, ac = 0.f;
    int scur = sp[0];
#pragma unroll
    for (int it = 0; it < 9; it++) {
        int s = sp[it];
        if (s != scur) {
            atomicAdd(&ls[scur * 4 + 0], a0);
            atomicAdd(&ls[scur * 4 + 1], a1);
            atomicAdd(&ls[scur * 4 + 2], a2);
            atomicAdd(&ls[scur * 4 + 3], ac);
            scur = s; a0 = a1 = a2 = ac = 0.f;
        }
        a0 += x0[it]; a1 += x1[it]; a2 += x2[it]; ac += 1.f;
    }
    atomicAdd(&ls[scur * 4 + 0], a0);
    atomicAdd(&ls[scur * 4 + 1], a1);
    atomicAdd(&ls[scur * 4 + 2], a2);
    atomicAdd(&ls[scur * 4 + 3], ac);
    __syncthreads();
    float* part = ws + (t * 16 + seg) * 1200;
    for (int i = tid; i < SS * 4; i += 256) part[i] = ls[i];
}

// ---- reduce partials -> transformed means (LDS + global for k_main),
//      then per-pixel max logit M and iZ, 2 px/thread ----
__launch_bounds__(256)
__global__ void k_prep(const float* __restrict__ x, float* __restrict__ ws) {
    __shared__ float4 sm[SP];
    const int tid = threadIdx.x;
    const int t = blockIdx.y;
    const float* part = ws + t * 16 * 1200;
    for (int i = tid; i < SP; i += 256) {
        float4 m;
        if (i < SS) {
            float s0 = 0.f, s1 = 0.f, s2 = 0.f, c = 0.f;
#pragma unroll
            for (int g = 0; g < 16; g++) {
                s0 += part[g * 1200 + i * 4 + 0];
                s1 += part[g * 1200 + i * 4 + 1];
                s2 += part[g * 1200 + i * 4 + 2];
                c  += part[g * 1200 + i * 4 + 3];
            }
            float inv = 1.f / fmaxf(c, 1.f);
            float mx = s0 * inv, my = s1 * inv, mz = s2 * inv;
            m.x = 20.f * LOG2E * mx; m.y = 20.f * LOG2E * my; m.z = 20.f * LOG2E * mz;
            m.w = (c > 0.f) ? (-10.f * LOG2E * (mx * mx + my * my + mz * mz)) : -INFINITY;
        } else {
            m.x = 0.f; m.y = 0.f; m.z = 0.f; m.w = -INFINITY;
        }
        sm[i] = m;
        if (blockIdx.x == 0) ((float4*)(ws + MEANS))[t * SP + i] = m;
    }
    __syncthreads();

    const int p0 = blockIdx.x * 512 + tid;
    const int p1 = p0 + 256;
    const float f0x = x[(t * 3 + 0) * HW + p0], f0y = x[(t * 3 + 1) * HW + p0], f0z = x[(t * 3 + 2) * HW + p0];
    const float f1x = x[(t * 3 + 0) * HW + p1], f1y = x[(t * 3 + 1) * HW + p1], f1z = x[(t * 3 + 2) * HW + p1];

    float M0 = -INFINITY, M1 = -INFINITY;
#pragma unroll 4
    for (int s = 0; s < SS; s++) {
        float4 a = sm[s];
        M0 = fmaxf(M0, fmaf(f0x, a.x, fmaf(f0y, a.y, fmaf(f0z, a.z, a.w))));
        M1 = fmaxf(M1, fmaf(f1x, a.x, fmaf(f1y, a.y, fmaf(f1z, a.z, a.w))));
    }
    float Z0 = 0.f, Z1 = 0.f;
#pragma unroll 4
    for (int s = 0; s < SS; s++) {
        float4 a = sm[s];
        Z0 += exp2f(fmaf(f0x, a.x, fmaf(f0y, a.y, fmaf(f0z, a.z, a.w))) - M0);
        Z1 += exp2f(fmaf(f1x, a.x, fmaf(f1y, a.y, fmaf(f1z, a.z, a.w))) - M1);
    }
    ws[MOFF + t * HW + p0] = M0;
    ws[MOFF + t * HW + p1] = M1;
    ws[ZOFF + t * HW + p0] = 1.f / Z0;
    ws[ZOFF + t * HW + p1] = 1.f / Z1;
}

#define REP49(M) M(0)M(1)M(2)M(3)M(4)M(5)M(6)M(7)M(8)M(9)M(10)M(11)M(12)M(13) \
    M(14)M(15)M(16)M(17)M(18)M(19)M(20)M(21)M(22)M(23)M(24)M(25)M(26)M(27) \
    M(28)M(29)M(30)M(31)M(32)M(33)M(34)M(35)M(36)M(37)M(38)M(39)M(40)M(41) \
    M(42)M(43)M(44)M(45)M(46)M(47)M(48)

#define QOFF(k) (((k) / 7 - PD) * HSZ + ((k) % 7 - PD))

// ================= fused: E (in-LDS) + MFMA attn + norm + linear =================
// Round-12 structure verbatim (512 threads, (512,2), means staged in LDS);
// only the ws offsets changed.

__launch_bounds__(512, 2)
__global__ void k_main(const float* __restrict__ x, const float* __restrict__ Wlin,
                       const float* __restrict__ blin, const float* __restrict__ ws,
                       float* __restrict__ out) {
    __shared__ __align__(16) char ebuf[2][NG * 16];   // 61952 B (attn overlay reuses this)
    __shared__ float4 sfh[NHP];                       // xyz = feature, w = iZ (0 if OOB)
    __shared__ float  sW[441];
    __shared__ float4 smean[SP];                      // 5120 B

    const int tid = threadIdx.x;
    const int wid = tid >> 6, lane = tid & 63;
    const int pxc = lane & 15, kg = lane >> 4;        // MFMA fragment coords
    const int t = blockIdx.z;
    const int gx0 = blockIdx.x * 16 - PD, gy0 = blockIdx.y * 16 - PD;
    const float4* m4 = (const float4*)(ws + MEANS) + t * SP;

    for (int i = tid; i < 441; i += 512) sW[i] = Wlin[i];
    for (int i = tid; i < SP; i += 512) smean[i] = m4[i];

    // ---- per-halo-pixel state (loads only; M/iZ precomputed) ----
    float fx = 0.f, fy = 0.f, fz = 0.f, M = INFINITY;
    if (tid < NHP) {
        int hy = tid / HSZ, hx = tid - hy * HSZ;
        int gy = gy0 + hy, gx = gx0 + hx;
        float iZ = 0.f;
        if (gy >= 0 && gy < HH && gx >= 0 && gx < WW) {
            int p = gy * WW + gx;
            fx = x[(t * 3 + 0) * HW + p];
            fy = x[(t * 3 + 1) * HW + p];
            fz = x[(t * 3 + 2) * HW + p];
            M  = ws[MOFF + t * HW + p];
            iZ = ws[ZOFF + t * HW + p];
        }
        sfh[tid] = make_float4(fx, fy, fz, iZ);
    }
    __syncthreads();   // smean (and sfh/sW) visible before PHASEB(0)

    // phase B: E values for chunk cc -> buffer bb (OOB px: M=+inf -> E=0)
#define PHASEB(cc, bb) if (tid < NHP) { \
        char* dst = ebuf[bb]; \
        _Pragma("unroll") \
        for (int jd = 0; jd < 4; jd++) { \
            h8 v; \
            _Pragma("unroll") \
            for (int e = 0; e < 4; e++) { \
                float4 ma = smean[(cc) * 32 + jd * 8 + 2 * e]; \
                float4 mb = smean[(cc) * 32 + jd * 8 + 2 * e + 1]; \
                float E0 = exp2f(fmaf(fx, ma.x, fmaf(fy, ma.y, fmaf(fz, ma.z, ma.w))) - M); \
                float E1 = exp2f(fmaf(fx, mb.x, fmaf(fy, mb.y, fmaf(fz, mb.z, mb.w))) - M); \
                auto pr = __builtin_amdgcn_cvt_pkrtz(E0, E1); \
                v[2 * e] = (_Float16)pr.x; v[2 * e + 1] = (_Float16)pr.y; \
            } \
            *(h8*)(dst + (jd * NHP + tid) * 16) = v; \
        } }

    // ---- MFMA setup: wave owns rows r0, r0+1 of the 16x16 tile ----
    const int r0 = 2 * wid;
    const int gA0 = kg * NHP + (r0 + PD) * HSZ + PD + pxc;          // A row r0
    const int gA1 = gA0 + HSZ;                                      // A row r0+1
    const int bcol2 = (16 + pxc > 21) ? 21 : 16 + pxc;              // clamped tile2 col
    const int gB1 = kg * NHP + r0 * HSZ + pxc;                      // + d*HSZ
    const int gB2 = kg * NHP + r0 * HSZ + bcol2;                    // + d*HSZ

    f4 zero4 = {0.f, 0.f, 0.f, 0.f};
    f4 aP[7], aQ[7], aR[7], aS[7];   // (A0,B1[d]) (A0,B2[d]) (A1,B1[d+1]) (A1,B2[d+1])
#pragma unroll
    for (int d = 0; d < 7; d++) { aP[d] = zero4; aQ[d] = zero4; aR[d] = zero4; aS[d] = zero4; }

    PHASEB(0, 0)

#pragma unroll 1
    for (int c = 0; c < 10; c++) {
        __syncthreads();               // phaseB(c) visible; MFMA(c-1) reads done
        if (c < 9) { PHASEB(c + 1, (c + 1) & 1) }
        const char* pb = ebuf[c & 1];
        h8 A0 = *(const h8*)(pb + gA0 * 16);
        h8 A1 = *(const h8*)(pb + gA1 * 16);
        // d = 0: B[0] feeds row r0 only
        h8 b1 = *(const h8*)(pb + gB1 * 16);
        h8 b2 = *(const h8*)(pb + gB2 * 16);
        aP[0] = __builtin_amdgcn_mfma_f32_16x16x32_f16(A0, b1, aP[0], 0, 0, 0);
        aQ[0] = __builtin_amdgcn_mfma_f32_16x16x32_f16(A0, b2, aQ[0], 0, 0, 0);
#pragma unroll
        for (int d = 1; d < 7; d++) {  // B[d] feeds row r0 (as d) and row r0+1 (as d-1)
            h8 n1 = *(const h8*)(pb + (gB1 + d * HSZ) * 16);
            h8 n2 = *(const h8*)(pb + (gB2 + d * HSZ) * 16);
            aP[d]     = __builtin_amdgcn_mfma_f32_16x16x32_f16(A0, n1, aP[d], 0, 0, 0);
            aR[d - 1] = __builtin_amdgcn_mfma_f32_16x16x32_f16(A1, n1, aR[d - 1], 0, 0, 0);
            aQ[d]     = __builtin_amdgcn_mfma_f32_16x16x32_f16(A0, n2, aQ[d], 0, 0, 0);
            aS[d - 1] = __builtin_amdgcn_mfma_f32_16x16x32_f16(A1, n2, aS[d - 1], 0, 0, 0);
        }
        // d = 7: B[7] feeds row r0+1 only
        h8 l1 = *(const h8*)(pb + (gB1 + 7 * HSZ) * 16);
        h8 l2 = *(const h8*)(pb + (gB2 + 7 * HSZ) * 16);
        aR[6] = __builtin_amdgcn_mfma_f32_16x16x32_f16(A1, l1, aR[6], 0, 0, 0);
        aS[6] = __builtin_amdgcn_mfma_f32_16x16x32_f16(A1, l2, aS[6], 0, 0, 0);
    }
    __syncthreads();                   // last MFMA reads done; ebuf reusable

    // ---- band write-out: D[i = 4*kg+reg, j = pxc] -> attn[px][k] (each slot once) ----
    float* attn = (float*)ebuf;        // [256 px][stride 51] f32, 52.2 KB < 62 KB
#pragma unroll
    for (int d = 0; d < 7; d++) {
#pragma unroll
        for (int reg = 0; reg < 4; reg++) {
            int i = 4 * kg + reg;
            int u1 = pxc - i;          // tile1: dx+3 = j-i
            int u2 = u1 + 16;          // tile2: dx+3 = 16+j-i
            if ((unsigned)u1 <= 6u) {
                attn[(r0 * 16 + i) * 51 + d * 7 + u1] = aP[d][reg];
                attn[((r0 + 1) * 16 + i) * 51 + d * 7 + u1] = aR[d][reg];
            }
            if ((unsigned)u2 <= 6u) {
                attn[(r0 * 16 + i) * 51 + d * 7 + u2] = aQ[d][reg];
                attn[((r0 + 1) * 16 + i) * 51 + d * 7 + u2] = aS[d][reg];
            }
        }
    }
    __syncthreads();

    // ---- normalize (eps+max semantics) + linear epilogue (1 thread / pixel) ----
    if (tid < 256) {
        const int r = tid >> 4, cq = tid & 15;
        const int own = (r + PD) * HSZ + (cq + PD);
        const float* ap = attn + tid * 51;
        float mx = 0.f;
#define PK1(k) mx = fmaxf(mx, ap[k] * sfh[own + QOFF(k)].w);
        REP49(PK1)
#undef PK1
        const float iZp = sfh[own].w;
        const float inv = 1.f / (1e-5f / iZp + mx);

        float o0 = blin[0], o1 = blin[1], o2 = blin[2];
#define PK2(k) { float4 f = sfh[own + QOFF(k)]; \
        float rwk = ap[k] * f.w * inv; \
        o0 += rwk * (sW[k] * f.x + sW[49 + (k)] * f.y + sW[98 + (k)] * f.z); \
        o1 += rwk * (sW[147 + (k)] * f.x + sW[196 + (k)] * f.y + sW[245 + (k)] * f.z); \
        o2 += rwk * (sW[294 + (k)] * f.x + sW[343 + (k)] * f.y + sW[392 + (k)] * f.z); }
        REP49(PK2)
#undef PK2

        int p = (gy0 + PD + r) * WW + gx0 + PD + cq;
        out[(t * 3 + 0) * HW + p] = o0;
        out[(t * 3 + 1) * HW + p] = o1;
        out[(t * 3 + 2) * HW + p] = o2;
    }
}

extern "C" void kernel_launch(void* const* d_in, const int* in_sizes, int n_in,
                              void* d_out, int out_size, void* d_ws, size_t ws_size,
                              hipStream_t stream) {
    (void)in_sizes; (void)n_in; (void)out_size; (void)ws_size;
    const float* x    = (const float*)d_in[0];
    const int*   spix = (const int*)d_in[1];
    const float* Wlin = (const float*)d_in[2];
    const float* blin = (const float*)d_in[3];
    float* out = (float*)d_out;
    float* ws  = (float*)d_ws;

    hipLaunchKernelGGL(k_accum, dim3(16, TT), dim3(256), 0, stream, x, spix, ws);
    hipLaunchKernelGGL(k_prep,  dim3(HW / 512, TT), dim3(256), 0, stream, x, ws);
    hipLaunchKernelGGL(k_main,  dim3(WW / 16, HH / 16, TT), dim3(512), 0, stream,
                       x, Wlin, blin, ws, out);
}

// Round 14
// 132.993 us; speedup vs baseline: 1.5252x; 1.0218x over previous
//
#include <hip/hip_runtime.h>
#include <math.h>

#define TT 4
#define HH 192
#define WW 192
#define SS 300
#define SP 320              // padded superpixel count (pad masked -inf)
#define HW (HH*WW)
#define PD 3
#define HSZ 22
#define NHP 484             // 22*22 halo pixels
#define PSTRG 486           // padded plane stride in 16B granules: bank shifts {0,24,16,8}
#define LOG2E 1.44269504088896340736f
#define NSEG 72             // accum segments per frame
#define MEANS 360448        // float index of means float4 [T][SP]
#define MOFF 393216         // float index of M table [T][HW]
#define ZOFF (MOFF + TT*HW) // float index of iZ table [T][HW]

typedef _Float16 h8 __attribute__((ext_vector_type(8)));
typedef float f4 __attribute__((ext_vector_type(4)));

// ---------- ws layout (floats) ----------
// [0, 345600)      partial sums [T][72 seg][300 s][4: sx,sy,sz,cnt]
// [MEANS, +5120)   means float4 [T][SP]: ((20/ln2)m, w = (-10/ln2)|m|^2 | -inf absent)
// [MOFF ...)       per-pixel max logit M (f32), then iZ = 1/Z (f32)

// per-segment partial sums: plain stores, no zeroed global table, no global atomics.
__launch_bounds__(256)
__global__ void k_accum(const float* __restrict__ x, const int* __restrict__ spix,
                        float* __restrict__ ws) {
    __shared__ float ls[SS * 4];
    const int tid = threadIdx.x;
    const int t = blockIdx.y, seg = blockIdx.x;
    for (int i = tid; i < SS * 4; i += 256) ls[i] = 0.f;
    __syncthreads();
    const int pb = seg * 512 + tid * 2;
#pragma unroll
    for (int it = 0; it < 2; it++) {
        int s = spix[t * HW + pb + it];
        atomicAdd(&ls[s * 4 + 0], x[(t * 3 + 0) * HW + pb + it]);
        atomicAdd(&ls[s * 4 + 1], x[(t * 3 + 1) * HW + pb + it]);
        atomicAdd(&ls[s * 4 + 2], x[(t * 3 + 2) * HW + pb + it]);
        atomicAdd(&ls[s * 4 + 3], 1.f);
    }
    __syncthreads();
    float* part = ws + (t * NSEG + seg) * 1200;
    for (int i = tid; i < SS * 4; i += 256) part[i] = ls[i];
}

// ---- reduce partials -> transformed means (LDS + global for k_main),
//      then per-pixel max logit M and iZ, 2 px/thread ----
__launch_bounds__(256)
__global__ void k_prep(const float* __restrict__ x, float* __restrict__ ws) {
    __shared__ float4 sm[SP];
    const int tid = threadIdx.x;
    const int t = blockIdx.y;
    const float* part = ws + t * NSEG * 1200;
    for (int i = tid; i < SP; i += 256) {
        float4 m;
        if (i < SS) {
            float s0 = 0.f, s1 = 0.f, s2 = 0.f, c = 0.f;
            for (int g = 0; g < NSEG; g++) {
                s0 += part[g * 1200 + i * 4 + 0];
                s1 += part[g * 1200 + i * 4 + 1];
                s2 += part[g * 1200 + i * 4 + 2];
                c  += part[g * 1200 + i * 4 + 3];
            }
            float inv = 1.f / fmaxf(c, 1.f);
            float mx = s0 * inv, my = s1 * inv, mz = s2 * inv;
            m.x = 20.f * LOG2E * mx; m.y = 20.f * LOG2E * my; m.z = 20.f * LOG2E * mz;
            m.w = (c > 0.f) ? (-10.f * LOG2E * (mx * mx + my * my + mz * mz)) : -INFINITY;
        } else {
            m.x = 0.f; m.y = 0.f; m.z = 0.f; m.w = -INFINITY;
        }
        sm[i] = m;
        if (blockIdx.x == 0) ((float4*)(ws + MEANS))[t * SP + i] = m;
    }
    __syncthreads();

    const int p0 = blockIdx.x * 512 + tid;
    const int p1 = p0 + 256;
    const float f0x = x[(t * 3 + 0) * HW + p0], f0y = x[(t * 3 + 1) * HW + p0], f0z = x[(t * 3 + 2) * HW + p0];
    const float f1x = x[(t * 3 + 0) * HW + p1], f1y = x[(t * 3 + 1) * HW + p1], f1z = x[(t * 3 + 2) * HW + p1];

    float M0 = -INFINITY, M1 = -INFINITY;
#pragma unroll 4
    for (int s = 0; s < SS; s++) {
        float4 a = sm[s];
        M0 = fmaxf(M0, fmaf(f0x, a.x, fmaf(f0y, a.y, fmaf(f0z, a.z, a.w))));
        M1 = fmaxf(M1, fmaf(f1x, a.x, fmaf(f1y, a.y, fmaf(f1z, a.z, a.w))));
    }
    float Z0 = 0.f, Z1 = 0.f;
#pragma unroll 4
    for (int s = 0; s < SS; s++) {
        float4 a = sm[s];
        Z0 += exp2f(fmaf(f0x, a.x, fmaf(f0y, a.y, fmaf(f0z, a.z, a.w))) - M0);
        Z1 += exp2f(fmaf(f1x, a.x, fmaf(f1y, a.y, fmaf(f1z, a.z, a.w))) - M1);
    }
    ws[MOFF + t * HW + p0] = M0;
    ws[MOFF + t * HW + p1] = M1;
    ws[ZOFF + t * HW + p0] = 1.f / Z0;
    ws[ZOFF + t * HW + p1] = 1.f / Z1;
}

#define REP49(M) M(0)M(1)M(2)M(3)M(4)M(5)M(6)M(7)M(8)M(9)M(10)M(11)M(12)M(13) \
    M(14)M(15)M(16)M(17)M(18)M(19)M(20)M(21)M(22)M(23)M(24)M(25)M(26)M(27) \
    M(28)M(29)M(30)M(31)M(32)M(33)M(34)M(35)M(36)M(37)M(38)M(39)M(40)M(41) \
    M(42)M(43)M(44)M(45)M(46)M(47)M(48)

#define QOFF(k) (((k) / 7 - PD) * HSZ + ((k) % 7 - PD))

// ================= fused: E (in-LDS) + MFMA attn + norm + linear =================
// Round-12 structure + (1) plane stride 486 granules (bank-conflict-free B reads),
// (2) wave-parity stagger of {MFMA(c), phaseB(c+1)} to halve per-pipe bursts,
// (3) setprio(1) around the MFMA cluster.

__launch_bounds__(512, 2)
__global__ void k_main(const float* __restrict__ x, const float* __restrict__ Wlin,
                       const float* __restrict__ blin, const float* __restrict__ ws,
                       float* __restrict__ out) {
    __shared__ __align__(16) char ebuf[2][4 * PSTRG * 16];   // 62208 B (attn overlay aliases)
    __shared__ float4 sfh[NHP];                       // xyz = feature, w = iZ (0 if OOB)
    __shared__ float  sW[441];
    __shared__ float4 smean[SP];                      // 5120 B

    const int tid = threadIdx.x;
    const int wid = tid >> 6, lane = tid & 63;
    const int pxc = lane & 15, kg = lane >> 4;        // MFMA fragment coords
    const int t = blockIdx.z;
    const int gx0 = blockIdx.x * 16 - PD, gy0 = blockIdx.y * 16 - PD;
    const float4* m4 = (const float4*)(ws + MEANS) + t * SP;

    for (int i = tid; i < 441; i += 512) sW[i] = Wlin[i];
    for (int i = tid; i < SP; i += 512) smean[i] = m4[i];

    // ---- per-halo-pixel state (loads only; M/iZ precomputed) ----
    float fx = 0.f, fy = 0.f, fz = 0.f, M = INFINITY;
    if (tid < NHP) {
        int hy = tid / HSZ, hx = tid - hy * HSZ;
        int gy = gy0 + hy, gx = gx0 + hx;
        float iZ = 0.f;
        if (gy >= 0 && gy < HH && gx >= 0 && gx < WW) {
            int p = gy * WW + gx;
            fx = x[(t * 3 + 0) * HW + p];
            fy = x[(t * 3 + 1) * HW + p];
            fz = x[(t * 3 + 2) * HW + p];
            M  = ws[MOFF + t * HW + p];
            iZ = ws[ZOFF + t * HW + p];
        }
        sfh[tid] = make_float4(fx, fy, fz, iZ);
    }
    __syncthreads();   // smean (and sfh/sW) visible before PHASEB(0)

    // phase B: E values for chunk cc -> buffer bb (OOB px: M=+inf -> E=0)
#define PHASEB(cc, bb) if (tid < NHP) { \
        char* dst = ebuf[bb]; \
        _Pragma("unroll") \
        for (int jd = 0; jd < 4; jd++) { \
            h8 v; \
            _Pragma("unroll") \
            for (int e = 0; e < 4; e++) { \
                float4 ma = smean[(cc) * 32 + jd * 8 + 2 * e]; \
                float4 mb = smean[(cc) * 32 + jd * 8 + 2 * e + 1]; \
                float E0 = exp2f(fmaf(fx, ma.x, fmaf(fy, ma.y, fmaf(fz, ma.z, ma.w))) - M); \
                float E1 = exp2f(fmaf(fx, mb.x, fmaf(fy, mb.y, fmaf(fz, mb.z, mb.w))) - M); \
                auto pr = __builtin_amdgcn_cvt_pkrtz(E0, E1); \
                v[2 * e] = (_Float16)pr.x; v[2 * e + 1] = (_Float16)pr.y; \
            } \
            *(h8*)(dst + (jd * PSTRG + tid) * 16) = v; \
        } }

    // ---- MFMA setup: wave owns rows r0, r0+1 of the 16x16 tile ----
    const int r0 = 2 * wid;
    const int gA0 = kg * PSTRG + (r0 + PD) * HSZ + PD + pxc;        // A row r0
    const int gA1 = gA0 + HSZ;                                      // A row r0+1
    const int bcol2 = (16 + pxc > 21) ? 21 : 16 + pxc;              // clamped tile2 col
    const int gB1 = kg * PSTRG + r0 * HSZ + pxc;                    // + d*HSZ
    const int gB2 = kg * PSTRG + r0 * HSZ + bcol2;                  // + d*HSZ

    f4 zero4 = {0.f, 0.f, 0.f, 0.f};
    f4 aP[7], aQ[7], aR[7], aS[7];   // (A0,B1[d]) (A0,B2[d]) (A1,B1[d+1]) (A1,B2[d+1])
#pragma unroll
    for (int d = 0; d < 7; d++) { aP[d] = zero4; aQ[d] = zero4; aR[d] = zero4; aS[d] = zero4; }

#define MFMA_CHUNK { \
        __builtin_amdgcn_s_setprio(1); \
        h8 A0 = *(const h8*)(pb + gA0 * 16); \
        h8 A1 = *(const h8*)(pb + gA1 * 16); \
        h8 b1 = *(const h8*)(pb + gB1 * 16); \
        h8 b2 = *(const h8*)(pb + gB2 * 16); \
        aP[0] = __builtin_amdgcn_mfma_f32_16x16x32_f16(A0, b1, aP[0], 0, 0, 0); \
        aQ[0] = __builtin_amdgcn_mfma_f32_16x16x32_f16(A0, b2, aQ[0], 0, 0, 0); \
        _Pragma("unroll") \
        for (int d = 1; d < 7; d++) { \
            h8 n1 = *(const h8*)(pb + (gB1 + d * HSZ) * 16); \
            h8 n2 = *(const h8*)(pb + (gB2 + d * HSZ) * 16); \
            aP[d]     = __builtin_amdgcn_mfma_f32_16x16x32_f16(A0, n1, aP[d], 0, 0, 0); \
            aR[d - 1] = __builtin_amdgcn_mfma_f32_16x16x32_f16(A1, n1, aR[d - 1], 0, 0, 0); \
            aQ[d]     = __builtin_amdgcn_mfma_f32_16x16x32_f16(A0, n2, aQ[d], 0, 0, 0); \
            aS[d - 1] = __builtin_amdgcn_mfma_f32_16x16x32_f16(A1, n2, aS[d - 1], 0, 0, 0); \
        } \
        h8 l1 = *(const h8*)(pb + (gB1 + 7 * HSZ) * 16); \
        h8 l2 = *(const h8*)(pb + (gB2 + 7 * HSZ) * 16); \
        aR[6] = __builtin_amdgcn_mfma_f32_16x16x32_f16(A1, l1, aR[6], 0, 0, 0); \
        aS[6] = __builtin_amdgcn_mfma_f32_16x16x32_f16(A1, l2, aS[6], 0, 0, 0); \
        __builtin_amdgcn_s_setprio(0); }

    PHASEB(0, 0)

#pragma unroll 1
    for (int c = 0; c < 10; c++) {
        __syncthreads();               // phaseB(c) visible; MFMA(c-1) reads done
        const char* pb = ebuf[c & 1];
        if (wid & 1) {                 // stagger: odd waves MFMA first
            MFMA_CHUNK
            if (c < 9) { PHASEB(c + 1, (c + 1) & 1) }
        } else {
            if (c < 9) { PHASEB(c + 1, (c + 1) & 1) }
            MFMA_CHUNK
        }
    }
    __syncthreads();                   // last MFMA reads done; ebuf reusable

    // ---- band write-out: D[i = 4*kg+reg, j = pxc] -> attn[px][k] (each slot once) ----
    float* attn = (float*)ebuf;        // [256 px][stride 51] f32, 52.2 KB < 62.2 KB
#pragma unroll
    for (int d = 0; d < 7; d++) {
#pragma unroll
        for (int reg = 0; reg < 4; reg++) {
            int i = 4 * kg + reg;
            int u1 = pxc - i;          // tile1: dx+3 = j-i
            int u2 = u1 + 16;          // tile2: dx+3 = 16+j-i
            if ((unsigned)u1 <= 6u) {
                attn[(r0 * 16 + i) * 51 + d * 7 + u1] = aP[d][reg];
                attn[((r0 + 1) * 16 + i) * 51 + d * 7 + u1] = aR[d][reg];
            }
            if ((unsigned)u2 <= 6u) {
                attn[(r0 * 16 + i) * 51 + d * 7 + u2] = aQ[d][reg];
                attn[((r0 + 1) * 16 + i) * 51 + d * 7 + u2] = aS[d][reg];
            }
        }
    }
    __syncthreads();

    // ---- normalize (eps+max semantics) + linear epilogue (1 thread / pixel) ----
    if (tid < 256) {
        const int r = tid >> 4, cq = tid & 15;
        const int own = (r + PD) * HSZ + (cq + PD);
        const float* ap = attn + tid * 51;
        float mx = 0.f;
#define PK1(k) mx = fmaxf(mx, ap[k] * sfh[own + QOFF(k)].w);
        REP49(PK1)
#undef PK1
        const float iZp = sfh[own].w;
        const float inv = 1.f / (1e-5f / iZp + mx);

        float o0 = blin[0], o1 = blin[1], o2 = blin[2];
#define PK2(k) { float4 f = sfh[own + QOFF(k)]; \
        float rwk = ap[k] * f.w * inv; \
        o0 += rwk * (sW[k] * f.x + sW[49 + (k)] * f.y + sW[98 + (k)] * f.z); \
        o1 += rwk * (sW[147 + (k)] * f.x + sW[196 + (k)] * f.y + sW[245 + (k)] * f.z); \
        o2 += rwk * (sW[294 + (k)] * f.x + sW[343 + (k)] * f.y + sW[392 + (k)] * f.z); }
        REP49(PK2)
#undef PK2

        int p = (gy0 + PD + r) * WW + gx0 + PD + cq;
        out[(t * 3 + 0) * HW + p] = o0;
        out[(t * 3 + 1) * HW + p] = o1;
        out[(t * 3 + 2) * HW + p] = o2;
    }
}

extern "C" void kernel_launch(void* const* d_in, const int* in_sizes, int n_in,
                              void* d_out, int out_size, void* d_ws, size_t ws_size,
                              hipStream_t stream) {
    (void)in_sizes; (void)n_in; (void)out_size; (void)ws_size;
    const float* x    = (const float*)d_in[0];
    const int*   spix = (const int*)d_in[1];
    const float* Wlin = (const float*)d_in[2];
    const float* blin = (const float*)d_in[3];
    float* out = (float*)d_out;
    float* ws  = (float*)d_ws;

    hipLaunchKernelGGL(k_accum, dim3(NSEG, TT), dim3(256), 0, stream, x, spix, ws);
    hipLaunchKernelGGL(k_prep,  dim3(HW / 512, TT), dim3(256), 0, stream, x, ws);
    hipLaunchKernelGGL(k_main,  dim3(WW / 16, HH / 16, TT), dim3(512), 0, stream,
                       x, Wlin, blin, ws, out);
}

// Round 15
// 131.330 us; speedup vs baseline: 1.5445x; 1.0127x over previous
//
#include <hip/hip_runtime.h>
#include <math.h>

#define TT 4
#define HH 192
#define WW 192
#define SS 300
#define SP 320              // padded superpixel count (pad masked -inf)
#define HW (HH*WW)
#define PD 3
#define HSZ 22
#define NHP 484             // 22*22 halo pixels
#define PSTRG 486           // padded plane stride in 16B granules (bank spread)
#define LOG2E 1.44269504088896340736f
#define NSEG 72             // accum segments per frame
#define MEANS 360448        // float index of means float4 [T][SP]
#define MOFF 393216         // float index of M table [T][HW]
#define ZOFF (MOFF + TT*HW) // float index of iZ table [T][HW]

typedef _Float16 h8 __attribute__((ext_vector_type(8)));
typedef float f4 __attribute__((ext_vector_type(4)));

// ---------- ws layout (floats) ----------
// [0, 345600)      partial sums [T][72 seg][300 s][4: sx,sy,sz,cnt]
// [MEANS, +5120)   means float4 [T][SP]: ((20/ln2)m, w = (-10/ln2)|m|^2 | -inf absent)
// [MOFF ...)       per-pixel max logit M (f32), then iZ = 1/Z (f32)

__launch_bounds__(256)
__global__ void k_accum(const float* __restrict__ x, const int* __restrict__ spix,
                        float* __restrict__ ws) {
    __shared__ float ls[SS * 4];
    const int tid = threadIdx.x;
    const int t = blockIdx.y, seg = blockIdx.x;
    for (int i = tid; i < SS * 4; i += 256) ls[i] = 0.f;
    __syncthreads();
    const int pb = seg * 512 + tid * 2;
#pragma unroll
    for (int it = 0; it < 2; it++) {
        int s = spix[t * HW + pb + it];
        atomicAdd(&ls[s * 4 + 0], x[(t * 3 + 0) * HW + pb + it]);
        atomicAdd(&ls[s * 4 + 1], x[(t * 3 + 1) * HW + pb + it]);
        atomicAdd(&ls[s * 4 + 2], x[(t * 3 + 2) * HW + pb + it]);
        atomicAdd(&ls[s * 4 + 3], 1.f);
    }
    __syncthreads();
    float* part = ws + (t * NSEG + seg) * 1200;
    for (int i = tid; i < SS * 4; i += 256) part[i] = ls[i];
}

__launch_bounds__(256)
__global__ void k_prep(const float* __restrict__ x, float* __restrict__ ws) {
    __shared__ float4 sm[SP];
    const int tid = threadIdx.x;
    const int t = blockIdx.y;
    const float* part = ws + t * NSEG * 1200;
    for (int i = tid; i < SP; i += 256) {
        float4 m;
        if (i < SS) {
            float s0 = 0.f, s1 = 0.f, s2 = 0.f, c = 0.f;
            for (int g = 0; g < NSEG; g++) {
                s0 += part[g * 1200 + i * 4 + 0];
                s1 += part[g * 1200 + i * 4 + 1];
                s2 += part[g * 1200 + i * 4 + 2];
                c  += part[g * 1200 + i * 4 + 3];
            }
            float inv = 1.f / fmaxf(c, 1.f);
            float mx = s0 * inv, my = s1 * inv, mz = s2 * inv;
            m.x = 20.f * LOG2E * mx; m.y = 20.f * LOG2E * my; m.z = 20.f * LOG2E * mz;
            m.w = (c > 0.f) ? (-10.f * LOG2E * (mx * mx + my * my + mz * mz)) : -INFINITY;
        } else {
            m.x = 0.f; m.y = 0.f; m.z = 0.f; m.w = -INFINITY;
        }
        sm[i] = m;
        if (blockIdx.x == 0) ((float4*)(ws + MEANS))[t * SP + i] = m;
    }
    __syncthreads();

    const int p0 = blockIdx.x * 512 + tid;
    const int p1 = p0 + 256;
    const float f0x = x[(t * 3 + 0) * HW + p0], f0y = x[(t * 3 + 1) * HW + p0], f0z = x[(t * 3 + 2) * HW + p0];
    const float f1x = x[(t * 3 + 0) * HW + p1], f1y = x[(t * 3 + 1) * HW + p1], f1z = x[(t * 3 + 2) * HW + p1];

    float M0 = -INFINITY, M1 = -INFINITY;
#pragma unroll 4
    for (int s = 0; s < SS; s++) {
        float4 a = sm[s];
        M0 = fmaxf(M0, fmaf(f0x, a.x, fmaf(f0y, a.y, fmaf(f0z, a.z, a.w))));
        M1 = fmaxf(M1, fmaf(f1x, a.x, fmaf(f1y, a.y, fmaf(f1z, a.z, a.w))));
    }
    float Z0 = 0.f, Z1 = 0.f;
#pragma unroll 4
    for (int s = 0; s < SS; s++) {
        float4 a = sm[s];
        Z0 += exp2f(fmaf(f0x, a.x, fmaf(f0y, a.y, fmaf(f0z, a.z, a.w))) - M0);
        Z1 += exp2f(fmaf(f1x, a.x, fmaf(f1y, a.y, fmaf(f1z, a.z, a.w))) - M1);
    }
    ws[MOFF + t * HW + p0] = M0;
    ws[MOFF + t * HW + p1] = M1;
    ws[ZOFF + t * HW + p0] = 1.f / Z0;
    ws[ZOFF + t * HW + p1] = 1.f / Z1;
}

#define REP49(M) M(0)M(1)M(2)M(3)M(4)M(5)M(6)M(7)M(8)M(9)M(10)M(11)M(12)M(13) \
    M(14)M(15)M(16)M(17)M(18)M(19)M(20)M(21)M(22)M(23)M(24)M(25)M(26)M(27) \
    M(28)M(29)M(30)M(31)M(32)M(33)M(34)M(35)M(36)M(37)M(38)M(39)M(40)M(41) \
    M(42)M(43)M(44)M(45)M(46)M(47)M(48)

#define QOFF(k) (((k) / 7 - PD) * HSZ + ((k) % 7 - PD))

// ================= fused: E (in-LDS) + MFMA attn + norm + linear =================
// SC=64 (8 planes/chunk): 5 chunks, half the barriers. ebuf dbuf = 124.4 KB
// (register-bound at 1 block/CU anyway -> LDS was idle). Two MFMA k-steps per
// chunk, depth-1 B-frag rotation prefetch inside each step.

__launch_bounds__(512, 2)
__global__ void k_main(const float* __restrict__ x, const float* __restrict__ Wlin,
                       const float* __restrict__ blin, const float* __restrict__ ws,
                       float* __restrict__ out) {
    __shared__ __align__(16) char ebuf[2][8 * PSTRG * 16];   // 124416 B (attn overlay aliases)
    __shared__ float4 sfh[NHP];                       // xyz = feature, w = iZ (0 if OOB)
    __shared__ float  sW[441];
    __shared__ float4 smean[SP];                      // 5120 B

    const int tid = threadIdx.x;
    const int wid = tid >> 6, lane = tid & 63;
    const int pxc = lane & 15, kg = lane >> 4;        // MFMA fragment coords
    const int t = blockIdx.z;
    const int gx0 = blockIdx.x * 16 - PD, gy0 = blockIdx.y * 16 - PD;
    const float4* m4 = (const float4*)(ws + MEANS) + t * SP;

    for (int i = tid; i < 441; i += 512) sW[i] = Wlin[i];
    for (int i = tid; i < SP; i += 512) smean[i] = m4[i];

    // ---- per-halo-pixel state (loads only; M/iZ precomputed) ----
    float fx = 0.f, fy = 0.f, fz = 0.f, M = INFINITY;
    if (tid < NHP) {
        int hy = tid / HSZ, hx = tid - hy * HSZ;
        int gy = gy0 + hy, gx = gx0 + hx;
        float iZ = 0.f;
        if (gy >= 0 && gy < HH && gx >= 0 && gx < WW) {
            int p = gy * WW + gx;
            fx = x[(t * 3 + 0) * HW + p];
            fy = x[(t * 3 + 1) * HW + p];
            fz = x[(t * 3 + 2) * HW + p];
            M  = ws[MOFF + t * HW + p];
            iZ = ws[ZOFF + t * HW + p];
        }
        sfh[tid] = make_float4(fx, fy, fz, iZ);
    }
    __syncthreads();   // smean (and sfh/sW) visible before PHASEB(0)

    // phase B: E for chunk cc (64 s = 8 planes) -> buffer bb (OOB px: M=+inf -> E=0)
#define PHASEB(cc, bb) if (tid < NHP) { \
        char* dst = ebuf[bb]; \
        _Pragma("unroll") \
        for (int jd = 0; jd < 8; jd++) { \
            h8 v; \
            _Pragma("unroll") \
            for (int e = 0; e < 4; e++) { \
                float4 ma = smean[(cc) * 64 + jd * 8 + 2 * e]; \
                float4 mb = smean[(cc) * 64 + jd * 8 + 2 * e + 1]; \
                float E0 = exp2f(fmaf(fx, ma.x, fmaf(fy, ma.y, fmaf(fz, ma.z, ma.w))) - M); \
                float E1 = exp2f(fmaf(fx, mb.x, fmaf(fy, mb.y, fmaf(fz, mb.z, mb.w))) - M); \
                auto pr = __builtin_amdgcn_cvt_pkrtz(E0, E1); \
                v[2 * e] = (_Float16)pr.x; v[2 * e + 1] = (_Float16)pr.y; \
            } \
            *(h8*)(dst + (jd * PSTRG + tid) * 16) = v; \
        } }

    // ---- MFMA setup: wave owns rows r0, r0+1 of the 16x16 tile ----
    const int r0 = 2 * wid;
    const int gA0 = kg * PSTRG + (r0 + PD) * HSZ + PD + pxc;        // A row r0
    const int gA1 = gA0 + HSZ;                                      // A row r0+1
    const int bcol2 = (16 + pxc > 21) ? 21 : 16 + pxc;              // clamped tile2 col
    const int gB1 = kg * PSTRG + r0 * HSZ + pxc;                    // + d*HSZ
    const int gB2 = kg * PSTRG + r0 * HSZ + bcol2;                  // + d*HSZ

    f4 zero4 = {0.f, 0.f, 0.f, 0.f};
    f4 aP[7], aQ[7], aR[7], aS[7];   // (A0,B1[d]) (A0,B2[d]) (A1,B1[d+1]) (A1,B2[d+1])
#pragma unroll
    for (int d = 0; d < 7; d++) { aP[d] = zero4; aQ[d] = zero4; aR[d] = zero4; aS[d] = zero4; }

    // one K=32 step (4 planes at pbk), depth-1 B rotation prefetch
#define MFMA_STEP(pbk) { \
        h8 A0 = *(const h8*)((pbk) + gA0 * 16); \
        h8 A1 = *(const h8*)((pbk) + gA1 * 16); \
        h8 c1 = *(const h8*)((pbk) + gB1 * 16); \
        h8 c2 = *(const h8*)((pbk) + gB2 * 16); \
        h8 n1 = *(const h8*)((pbk) + (gB1 + HSZ) * 16); \
        h8 n2 = *(const h8*)((pbk) + (gB2 + HSZ) * 16); \
        aP[0] = __builtin_amdgcn_mfma_f32_16x16x32_f16(A0, c1, aP[0], 0, 0, 0); \
        aQ[0] = __builtin_amdgcn_mfma_f32_16x16x32_f16(A0, c2, aQ[0], 0, 0, 0); \
        _Pragma("unroll") \
        for (int d = 1; d < 7; d++) { \
            h8 f1 = *(const h8*)((pbk) + (gB1 + (d + 1) * HSZ) * 16); \
            h8 f2 = *(const h8*)((pbk) + (gB2 + (d + 1) * HSZ) * 16); \
            aP[d]     = __builtin_amdgcn_mfma_f32_16x16x32_f16(A0, n1, aP[d], 0, 0, 0); \
            aR[d - 1] = __builtin_amdgcn_mfma_f32_16x16x32_f16(A1, n1, aR[d - 1], 0, 0, 0); \
            aQ[d]     = __builtin_amdgcn_mfma_f32_16x16x32_f16(A0, n2, aQ[d], 0, 0, 0); \
            aS[d - 1] = __builtin_amdgcn_mfma_f32_16x16x32_f16(A1, n2, aS[d - 1], 0, 0, 0); \
            n1 = f1; n2 = f2; \
        } \
        aR[6] = __builtin_amdgcn_mfma_f32_16x16x32_f16(A1, n1, aR[6], 0, 0, 0); \
        aS[6] = __builtin_amdgcn_mfma_f32_16x16x32_f16(A1, n2, aS[6], 0, 0, 0); }

#define MFMA_CHUNK { \
        __builtin_amdgcn_s_setprio(1); \
        MFMA_STEP(pb) \
        MFMA_STEP(pb + 4 * PSTRG * 16) \
        __builtin_amdgcn_s_setprio(0); }

    PHASEB(0, 0)

#pragma unroll 1
    for (int c = 0; c < 5; c++) {
        __syncthreads();               // phaseB(c) visible; MFMA(c-1) reads done
        const char* pb = ebuf[c & 1];
        if (wid & 1) {                 // stagger: odd waves MFMA first
            MFMA_CHUNK
            if (c < 4) { PHASEB(c + 1, (c + 1) & 1) }
        } else {
            if (c < 4) { PHASEB(c + 1, (c + 1) & 1) }
            MFMA_CHUNK
        }
    }
    __syncthreads();                   // last MFMA reads done; ebuf reusable

    // ---- band write-out: D[i = 4*kg+reg, j = pxc] -> attn[px][k] (each slot once) ----
    float* attn = (float*)ebuf;        // [256 px][stride 51] f32, 52.2 KB
#pragma unroll
    for (int d = 0; d < 7; d++) {
#pragma unroll
        for (int reg = 0; reg < 4; reg++) {
            int i = 4 * kg + reg;
            int u1 = pxc - i;          // tile1: dx+3 = j-i
            int u2 = u1 + 16;          // tile2: dx+3 = 16+j-i
            if ((unsigned)u1 <= 6u) {
                attn[(r0 * 16 + i) * 51 + d * 7 + u1] = aP[d][reg];
                attn[((r0 + 1) * 16 + i) * 51 + d * 7 + u1] = aR[d][reg];
            }
            if ((unsigned)u2 <= 6u) {
                attn[(r0 * 16 + i) * 51 + d * 7 + u2] = aQ[d][reg];
                attn[((r0 + 1) * 16 + i) * 51 + d * 7 + u2] = aS[d][reg];
            }
        }
    }
    __syncthreads();

    // ---- normalize (eps+max semantics) + linear epilogue (1 thread / pixel) ----
    if (tid < 256) {
        const int r = tid >> 4, cq = tid & 15;
        const int own = (r + PD) * HSZ + (cq + PD);
        const float* ap = attn + tid * 51;
        float mx = 0.f;
#define PK1(k) mx = fmaxf(mx, ap[k] * sfh[own + QOFF(k)].w);
        REP49(PK1)
#undef PK1
        const float iZp = sfh[own].w;
        const float inv = 1.f / (1e-5f / iZp + mx);

        float o0 = blin[0], o1 = blin[1], o2 = blin[2];
#define PK2(k) { float4 f = sfh[own + QOFF(k)]; \
        float rwk = ap[k] * f.w * inv; \
        o0 += rwk * (sW[k] * f.x + sW[49 + (k)] * f.y + sW[98 + (k)] * f.z); \
        o1 += rwk * (sW[147 + (k)] * f.x + sW[196 + (k)] * f.y + sW[245 + (k)] * f.z); \
        o2 += rwk * (sW[294 + (k)] * f.x + sW[343 + (k)] * f.y + sW[392 + (k)] * f.z); }
        REP49(PK2)
#undef PK2

        int p = (gy0 + PD + r) * WW + gx0 + PD + cq;
        out[(t * 3 + 0) * HW + p] = o0;
        out[(t * 3 + 1) * HW + p] = o1;
        out[(t * 3 + 2) * HW + p] = o2;
    }
}

extern "C" void kernel_launch(void* const* d_in, const int* in_sizes, int n_in,
                              void* d_out, int out_size, void* d_ws, size_t ws_size,
                              hipStream_t stream) {
    (void)in_sizes; (void)n_in; (void)out_size; (void)ws_size;
    const float* x    = (const float*)d_in[0];
    const int*   spix = (const int*)d_in[1];
    const float* Wlin = (const float*)d_in[2];
    const float* blin = (const float*)d_in[3];
    float* out = (float*)d_out;
    float* ws  = (float*)d_ws;

    hipLaunchKernelGGL(k_accum, dim3(NSEG, TT), dim3(256), 0, stream, x, spix, ws);
    hipLaunchKernelGGL(k_prep,  dim3(HW / 512, TT), dim3(256), 0, stream, x, ws);
    hipLaunchKernelGGL(k_main,  dim3(WW / 16, HH / 16, TT), dim3(512), 0, stream,
                       x, Wlin, blin, ws, out);
}

// Round 16
// 116.358 us; speedup vs baseline: 1.7433x; 1.1287x over previous
//
#include <hip/hip_runtime.h>
#include <math.h>

#define TT 4
#define HH 192
#define WW 192
#define SS 300
#define SP 320              // padded superpixel count (pad masked -inf)
#define HW (HH*WW)
#define PD 3
#define TSW 12              // tile width  -> grid 16 x 12 x 4 = 768 = 3 x 256 (balanced)
#define TSH 16              // tile height
#define HLW 18              // halo width  = row stride
#define HLH 22              // halo height
#define NHP (HLH*HLW)       // 396 halo pixels
#define PSTRG 400           // plane stride in 16B granules
#define NSEG 72             // accum segments per frame
#define MEANS 360448        // float index of means float4 [T][SP]
#define MOFF 393216         // float index of M table [T][HW]
#define ZOFF (MOFF + TT*HW) // float index of iZ table [T][HW]

typedef _Float16 h8 __attribute__((ext_vector_type(8)));
typedef float f4 __attribute__((ext_vector_type(4)));

// ---------- ws layout (floats) ----------
// [0, 345600)      partial sums [T][72 seg][300 s][4: sx,sy,sz,cnt]
// [MEANS, +5120)   means float4 [T][SP]: (20m, w = -10|m|^2 | -inf absent)  [e-base]
// [MOFF ...)       per-pixel max logit M (f32), then iZ = 1/Z (f32)

__launch_bounds__(256)
__global__ void k_accum(const float* __restrict__ x, const int* __restrict__ spix,
                        float* __restrict__ ws) {
    __shared__ float ls[SS * 4];
    const int tid = threadIdx.x;
    const int t = blockIdx.y, seg = blockIdx.x;
    for (int i = tid; i < SS * 4; i += 256) ls[i] = 0.f;
    __syncthreads();
    const int pb = seg * 512 + tid * 2;
#pragma unroll
    for (int it = 0; it < 2; it++) {
        int s = spix[t * HW + pb + it];
        atomicAdd(&ls[s * 4 + 0], x[(t * 3 + 0) * HW + pb + it]);
        atomicAdd(&ls[s * 4 + 1], x[(t * 3 + 1) * HW + pb + it]);
        atomicAdd(&ls[s * 4 + 2], x[(t * 3 + 2) * HW + pb + it]);
        atomicAdd(&ls[s * 4 + 3], 1.f);
    }
    __syncthreads();
    float* part = ws + (t * NSEG + seg) * 1200;
    for (int i = tid; i < SS * 4; i += 256) part[i] = ls[i];
}

__launch_bounds__(256)
__global__ void k_prep(const float* __restrict__ x, float* __restrict__ ws) {
    __shared__ float4 sm[SP];
    const int tid = threadIdx.x;
    const int t = blockIdx.y;
    const float* part = ws + t * NSEG * 1200;
    for (int i = tid; i < SP; i += 256) {
        float4 m;
        if (i < SS) {
            float s0 = 0.f, s1 = 0.f, s2 = 0.f, c = 0.f;
            for (int g = 0; g < NSEG; g++) {
                s0 += part[g * 1200 + i * 4 + 0];
                s1 += part[g * 1200 + i * 4 + 1];
                s2 += part[g * 1200 + i * 4 + 2];
                c  += part[g * 1200 + i * 4 + 3];
            }
            float inv = 1.f / fmaxf(c, 1.f);
            float mx = s0 * inv, my = s1 * inv, mz = s2 * inv;
            m.x = 20.f * mx; m.y = 20.f * my; m.z = 20.f * mz;
            m.w = (c > 0.f) ? (-10.f * (mx * mx + my * my + mz * mz)) : -INFINITY;
        } else {
            m.x = 0.f; m.y = 0.f; m.z = 0.f; m.w = -INFINITY;
        }
        sm[i] = m;
        if (blockIdx.x == 0) ((float4*)(ws + MEANS))[t * SP + i] = m;
    }
    __syncthreads();

    const int p0 = blockIdx.x * 512 + tid;
    const int p1 = p0 + 256;
    const float f0x = x[(t * 3 + 0) * HW + p0], f0y = x[(t * 3 + 1) * HW + p0], f0z = x[(t * 3 + 2) * HW + p0];
    const float f1x = x[(t * 3 + 0) * HW + p1], f1y = x[(t * 3 + 1) * HW + p1], f1z = x[(t * 3 + 2) * HW + p1];

    float M0 = -INFINITY, M1 = -INFINITY;
#pragma unroll 4
    for (int s = 0; s < SS; s++) {
        float4 a = sm[s];
        M0 = fmaxf(M0, fmaf(f0x, a.x, fmaf(f0y, a.y, fmaf(f0z, a.z, a.w))));
        M1 = fmaxf(M1, fmaf(f1x, a.x, fmaf(f1y, a.y, fmaf(f1z, a.z, a.w))));
    }
    float Z0 = 0.f, Z1 = 0.f;
#pragma unroll 4
    for (int s = 0; s < SS; s++) {
        float4 a = sm[s];
        Z0 += __expf(fmaf(f0x, a.x, fmaf(f0y, a.y, fmaf(f0z, a.z, a.w))) - M0);
        Z1 += __expf(fmaf(f1x, a.x, fmaf(f1y, a.y, fmaf(f1z, a.z, a.w))) - M1);
    }
    ws[MOFF + t * HW + p0] = M0;
    ws[MOFF + t * HW + p1] = M1;
    ws[ZOFF + t * HW + p0] = 1.f / Z0;
    ws[ZOFF + t * HW + p1] = 1.f / Z1;
}

#define REP49(M) M(0)M(1)M(2)M(3)M(4)M(5)M(6)M(7)M(8)M(9)M(10)M(11)M(12)M(13) \
    M(14)M(15)M(16)M(17)M(18)M(19)M(20)M(21)M(22)M(23)M(24)M(25)M(26)M(27) \
    M(28)M(29)M(30)M(31)M(32)M(33)M(34)M(35)M(36)M(37)M(38)M(39)M(40)M(41) \
    M(42)M(43)M(44)M(45)M(46)M(47)M(48)

#define QOFF(k) (((k) / 7 - PD) * HLW + ((k) % 7 - PD))

// ================= fused: E (in-LDS) + MFMA attn + norm + linear =================
// 12x16 tile, 512 threads. SC=64 (8 planes/chunk), 5 chunks, dbuf. Wave owns tile
// rows r0,r0+1; A = output-row px (cols clamped; D rows i>=12 garbage, masked at
// write-out). __expf = native v_exp path (no precise-libm exp2).

__launch_bounds__(512, 2)
__global__ void k_main(const float* __restrict__ x, const float* __restrict__ Wlin,
                       const float* __restrict__ blin, const float* __restrict__ ws,
                       float* __restrict__ out) {
    __shared__ __align__(16) char ebuf[2][8 * PSTRG * 16];   // 102400 B (attn overlay aliases)
    __shared__ float4 sfh[NHP];                       // xyz = feature, w = iZ (0 if OOB)
    __shared__ float  sW[441];
    __shared__ float4 smean[SP];                      // 5120 B

    const int tid = threadIdx.x;
    const int wid = tid >> 6, lane = tid & 63;
    const int pxc = lane & 15, kg = lane >> 4;        // MFMA fragment coords
    const int t = blockIdx.z;
    const int gx0 = blockIdx.x * TSW - PD, gy0 = blockIdx.y * TSH - PD;
    const float4* m4 = (const float4*)(ws + MEANS) + t * SP;

    for (int i = tid; i < 441; i += 512) sW[i] = Wlin[i];
    for (int i = tid; i < SP; i += 512) smean[i] = m4[i];

    // ---- per-halo-pixel state (loads only; M/iZ precomputed) ----
    float fx = 0.f, fy = 0.f, fz = 0.f, M = INFINITY;
    if (tid < NHP) {
        int hy = tid / HLW, hx = tid - hy * HLW;
        int gy = gy0 + hy, gx = gx0 + hx;
        float iZ = 0.f;
        if (gy >= 0 && gy < HH && gx >= 0 && gx < WW) {
            int p = gy * WW + gx;
            fx = x[(t * 3 + 0) * HW + p];
            fy = x[(t * 3 + 1) * HW + p];
            fz = x[(t * 3 + 2) * HW + p];
            M  = ws[MOFF + t * HW + p];
            iZ = ws[ZOFF + t * HW + p];
        }
        sfh[tid] = make_float4(fx, fy, fz, iZ);
    }
    __syncthreads();   // smean (and sfh/sW) visible before PHASEB(0)

    // phase B: E for chunk cc (64 s = 8 planes) -> buffer bb (OOB px: M=+inf -> E=0)
#define PHASEB(cc, bb) if (tid < NHP) { \
        char* dst = ebuf[bb]; \
        _Pragma("unroll") \
        for (int jd = 0; jd < 8; jd++) { \
            h8 v; \
            _Pragma("unroll") \
            for (int e = 0; e < 4; e++) { \
                float4 ma = smean[(cc) * 64 + jd * 8 + 2 * e]; \
                float4 mb = smean[(cc) * 64 + jd * 8 + 2 * e + 1]; \
                float E0 = __expf(fmaf(fx, ma.x, fmaf(fy, ma.y, fmaf(fz, ma.z, ma.w))) - M); \
                float E1 = __expf(fmaf(fx, mb.x, fmaf(fy, mb.y, fmaf(fz, mb.z, mb.w))) - M); \
                auto pr = __builtin_amdgcn_cvt_pkrtz(E0, E1); \
                v[2 * e] = (_Float16)pr.x; v[2 * e + 1] = (_Float16)pr.y; \
            } \
            *(h8*)(dst + (jd * PSTRG + tid) * 16) = v; \
        } }

    // ---- MFMA setup: wave owns tile rows r0, r0+1 ----
    const int r0 = 2 * wid;
    const int acol = (pxc > 14) ? 14 : pxc;                         // A col clamp (i>=12 masked)
    const int gA0 = kg * PSTRG + (r0 + PD) * HLW + PD + acol;       // A row r0
    const int gA1 = gA0 + HLW;                                      // A row r0+1
    const int bcol2 = (16 + pxc > 17) ? 17 : 16 + pxc;              // clamped tile2 col
    const int gB1 = kg * PSTRG + r0 * HLW + pxc;                    // + d*HLW
    const int gB2 = kg * PSTRG + r0 * HLW + bcol2;                  // + d*HLW

    f4 zero4 = {0.f, 0.f, 0.f, 0.f};
    f4 aP[7], aQ[7], aR[7], aS[7];   // (A0,B1[d]) (A0,B2[d]) (A1,B1[d+1]) (A1,B2[d+1])
#pragma unroll
    for (int d = 0; d < 7; d++) { aP[d] = zero4; aQ[d] = zero4; aR[d] = zero4; aS[d] = zero4; }

    // one K=32 step (4 planes at pbk), depth-1 B rotation prefetch
#define MFMA_STEP(pbk) { \
        h8 A0 = *(const h8*)((pbk) + gA0 * 16); \
        h8 A1 = *(const h8*)((pbk) + gA1 * 16); \
        h8 c1 = *(const h8*)((pbk) + gB1 * 16); \
        h8 c2 = *(const h8*)((pbk) + gB2 * 16); \
        h8 n1 = *(const h8*)((pbk) + (gB1 + HLW) * 16); \
        h8 n2 = *(const h8*)((pbk) + (gB2 + HLW) * 16); \
        aP[0] = __builtin_amdgcn_mfma_f32_16x16x32_f16(A0, c1, aP[0], 0, 0, 0); \
        aQ[0] = __builtin_amdgcn_mfma_f32_16x16x32_f16(A0, c2, aQ[0], 0, 0, 0); \
        _Pragma("unroll") \
        for (int d = 1; d < 7; d++) { \
            h8 f1 = *(const h8*)((pbk) + (gB1 + (d + 1) * HLW) * 16); \
            h8 f2 = *(const h8*)((pbk) + (gB2 + (d + 1) * HLW) * 16); \
            aP[d]     = __builtin_amdgcn_mfma_f32_16x16x32_f16(A0, n1, aP[d], 0, 0, 0); \
            aR[d - 1] = __builtin_amdgcn_mfma_f32_16x16x32_f16(A1, n1, aR[d - 1], 0, 0, 0); \
            aQ[d]     = __builtin_amdgcn_mfma_f32_16x16x32_f16(A0, n2, aQ[d], 0, 0, 0); \
            aS[d - 1] = __builtin_amdgcn_mfma_f32_16x16x32_f16(A1, n2, aS[d - 1], 0, 0, 0); \
            n1 = f1; n2 = f2; \
        } \
        aR[6] = __builtin_amdgcn_mfma_f32_16x16x32_f16(A1, n1, aR[6], 0, 0, 0); \
        aS[6] = __builtin_amdgcn_mfma_f32_16x16x32_f16(A1, n2, aS[6], 0, 0, 0); }

#define MFMA_CHUNK { \
        __builtin_amdgcn_s_setprio(1); \
        MFMA_STEP(pb) \
        MFMA_STEP(pb + 4 * PSTRG * 16) \
        __builtin_amdgcn_s_setprio(0); }

    PHASEB(0, 0)

#pragma unroll 1
    for (int c = 0; c < 5; c++) {
        __syncthreads();               // phaseB(c) visible; MFMA(c-1) reads done
        const char* pb = ebuf[c & 1];
        if (wid & 1) {                 // stagger: odd waves MFMA first
            MFMA_CHUNK
            if (c < 4) { PHASEB(c + 1, (c + 1) & 1) }
        } else {
            if (c < 4) { PHASEB(c + 1, (c + 1) & 1) }
            MFMA_CHUNK
        }
    }
    __syncthreads();                   // last MFMA reads done; ebuf reusable

    // ---- band write-out: D[i,j] -> attn[px][k]; rows i>=12 are garbage (masked) ----
    float* attn = (float*)ebuf;        // [192 px][stride 51] f32, 39.2 KB
#pragma unroll
    for (int d = 0; d < 7; d++) {
#pragma unroll
        for (int reg = 0; reg < 4; reg++) {
            int i = 4 * kg + reg;
            int u1 = pxc - i;          // tile1: dx+3 = j-i
            int u2 = u1 + 16;          // tile2: dx+3 = 16+j-i
            if (i < TSW) {
                if ((unsigned)u1 <= 6u) {
                    attn[(r0 * TSW + i) * 51 + d * 7 + u1] = aP[d][reg];
                    attn[((r0 + 1) * TSW + i) * 51 + d * 7 + u1] = aR[d][reg];
                }
                if ((unsigned)u2 <= 6u) {
                    attn[(r0 * TSW + i) * 51 + d * 7 + u2] = aQ[d][reg];
                    attn[((r0 + 1) * TSW + i) * 51 + d * 7 + u2] = aS[d][reg];
                }
            }
        }
    }
    __syncthreads();

    // ---- normalize (eps+max semantics) + linear epilogue (1 thread / pixel) ----
    if (tid < TSH * TSW) {
        const int r = tid / TSW, cq = tid - r * TSW;
        const int own = (r + PD) * HLW + (cq + PD);
        const float* ap = attn + tid * 51;
        float mx = 0.f;
#define PK1(k) mx = fmaxf(mx, ap[k] * sfh[own + QOFF(k)].w);
        REP49(PK1)
#undef PK1
        const float iZp = sfh[own].w;
        const float inv = 1.f / (1e-5f / iZp + mx);

        float o0 = blin[0], o1 = blin[1], o2 = blin[2];
#define PK2(k) { float4 f = sfh[own + QOFF(k)]; \
        float rwk = ap[k] * f.w * inv; \
        o0 += rwk * (sW[k] * f.x + sW[49 + (k)] * f.y + sW[98 + (k)] * f.z); \
        o1 += rwk * (sW[147 + (k)] * f.x + sW[196 + (k)] * f.y + sW[245 + (k)] * f.z); \
        o2 += rwk * (sW[294 + (k)] * f.x + sW[343 + (k)] * f.y + sW[392 + (k)] * f.z); }
        REP49(PK2)
#undef PK2

        int p = (gy0 + PD + r) * WW + gx0 + PD + cq;
        out[(t * 3 + 0) * HW + p] = o0;
        out[(t * 3 + 1) * HW + p] = o1;
        out[(t * 3 + 2) * HW + p] = o2;
    }
}

extern "C" void kernel_launch(void* const* d_in, const int* in_sizes, int n_in,
                              void* d_out, int out_size, void* d_ws, size_t ws_size,
                              hipStream_t stream) {
    (void)in_sizes; (void)n_in; (void)out_size; (void)ws_size;
    const float* x    = (const float*)d_in[0];
    const int*   spix = (const int*)d_in[1];
    const float* Wlin = (const float*)d_in[2];
    const float* blin = (const float*)d_in[3];
    float* out = (float*)d_out;
    float* ws  = (float*)d_ws;

    hipLaunchKernelGGL(k_accum, dim3(NSEG, TT), dim3(256), 0, stream, x, spix, ws);
    hipLaunchKernelGGL(k_prep,  dim3(HW / 512, TT), dim3(256), 0, stream, x, ws);
    hipLaunchKernelGGL(k_main,  dim3(WW / TSW, HH / TSH, TT), dim3(512), 0, stream,
                       x, Wlin, blin, ws, out);
}

// Round 19
// 111.981 us; speedup vs baseline: 1.8114x; 1.0391x over previous
//
#include <hip/hip_runtime.h>
#include <math.h>

#define TT 4
#define HH 192
#define WW 192
#define SS 300
#define SP 320              // padded superpixel count (pad masked -inf)
#define HW (HH*WW)          // 36864
#define PD 3
#define TSW 12              // tile width  -> grid 16 x 12 x 4 = 768 = 3 x 256 (balanced)
#define TSH 16              // tile height
#define HLW 18              // halo width  = row stride
#define HLH 22              // halo height
#define NHP (HLH*HLW)       // 396 halo pixels
#define PSTRG 400           // plane stride in 16B granules
#define NSEG 48             // accum segments per frame: 48 x 768 px = HW exactly
#define MEANS 360448        // float index of means float4 [T][SP]
#define MOFF 393216         // float index of packed {M, iZ} float2 table [T][HW]

typedef _Float16 h8 __attribute__((ext_vector_type(8)));
typedef float f4 __attribute__((ext_vector_type(4)));

// ---------- ws layout (floats) ----------
// [0, 230400)      partial sums [T][48 seg][300 s][4: sx,sy,sz,cnt]
// [MEANS, +5120)   means float4 [T][SP]: (20m, w = -10|m|^2 | -inf absent)  [e-base]
// [MOFF ...)       packed per-pixel {max logit M, iZ = 1/Z} float2 [T][HW]

__launch_bounds__(256)
__global__ void k_accum(const float* __restrict__ x, const int* __restrict__ spix,
                        float* __restrict__ ws) {
    __shared__ float ls[SS * 4];
    const int tid = threadIdx.x;
    const int t = blockIdx.y, seg = blockIdx.x;
    for (int i = tid; i < SS * 4; i += 256) ls[i] = 0.f;
    __syncthreads();
#pragma unroll
    for (int it = 0; it < 3; it++) {
        int px = seg * 768 + it * 256 + tid;            // 48*768 = 36864 = HW
        int s = spix[t * HW + px];
        atomicAdd(&ls[s * 4 + 0], x[(t * 3 + 0) * HW + px]);
        atomicAdd(&ls[s * 4 + 1], x[(t * 3 + 1) * HW + px]);
        atomicAdd(&ls[s * 4 + 2], x[(t * 3 + 2) * HW + px]);
        atomicAdd(&ls[s * 4 + 3], 1.f);
    }
    __syncthreads();
    float* part = ws + (t * NSEG + seg) * 1200;
    for (int i = tid; i < SS * 4; i += 256) part[i] = ls[i];
}

// ---- reduce partials -> transformed means; per-pixel {M, iZ} (3 px/thread) ----
__launch_bounds__(256)
__global__ void k_prep(const float* __restrict__ x, float* __restrict__ ws) {
    __shared__ float4 sm[SP];
    const int tid = threadIdx.x;
    const int t = blockIdx.y;
    const float* part = ws + t * NSEG * 1200;
    for (int i = tid; i < SP; i += 256) {
        float4 m;
        if (i < SS) {
            float s0 = 0.f, s1 = 0.f, s2 = 0.f, c = 0.f;
            for (int g = 0; g < NSEG; g++) {
                s0 += part[g * 1200 + i * 4 + 0];
                s1 += part[g * 1200 + i * 4 + 1];
                s2 += part[g * 1200 + i * 4 + 2];
                c  += part[g * 1200 + i * 4 + 3];
            }
            float inv = 1.f / fmaxf(c, 1.f);
            float mx = s0 * inv, my = s1 * inv, mz = s2 * inv;
            m.x = 20.f * mx; m.y = 20.f * my; m.z = 20.f * mz;
            m.w = (c > 0.f) ? (-10.f * (mx * mx + my * my + mz * mz)) : -INFINITY;
        } else {
            m.x = 0.f; m.y = 0.f; m.z = 0.f; m.w = -INFINITY;
        }
        sm[i] = m;
        if (blockIdx.x == 0) ((float4*)(ws + MEANS))[t * SP + i] = m;
    }
    __syncthreads();

    const int p0 = blockIdx.x * 768 + tid;              // 48 blocks x 768 px = HW
    const int p1 = p0 + 256, p2 = p0 + 512;
    const float f0x = x[(t * 3 + 0) * HW + p0], f0y = x[(t * 3 + 1) * HW + p0], f0z = x[(t * 3 + 2) * HW + p0];
    const float f1x = x[(t * 3 + 0) * HW + p1], f1y = x[(t * 3 + 1) * HW + p1], f1z = x[(t * 3 + 2) * HW + p1];
    const float f2x = x[(t * 3 + 0) * HW + p2], f2y = x[(t * 3 + 1) * HW + p2], f2z = x[(t * 3 + 2) * HW + p2];

    float M0 = -INFINITY, M1 = -INFINITY, M2 = -INFINITY;
#pragma unroll 4
    for (int s = 0; s < SS; s++) {
        float4 a = sm[s];
        M0 = fmaxf(M0, fmaf(f0x, a.x, fmaf(f0y, a.y, fmaf(f0z, a.z, a.w))));
        M1 = fmaxf(M1, fmaf(f1x, a.x, fmaf(f1y, a.y, fmaf(f1z, a.z, a.w))));
        M2 = fmaxf(M2, fmaf(f2x, a.x, fmaf(f2y, a.y, fmaf(f2z, a.z, a.w))));
    }
    float Z0 = 0.f, Z1 = 0.f, Z2 = 0.f;
#pragma unroll 4
    for (int s = 0; s < SS; s++) {
        float4 a = sm[s];
        Z0 += __expf(fmaf(f0x, a.x, fmaf(f0y, a.y, fmaf(f0z, a.z, a.w))) - M0);
        Z1 += __expf(fmaf(f1x, a.x, fmaf(f1y, a.y, fmaf(f1z, a.z, a.w))) - M1);
        Z2 += __expf(fmaf(f2x, a.x, fmaf(f2y, a.y, fmaf(f2z, a.z, a.w))) - M2);
    }
    float2* mzt = (float2*)(ws + MOFF) + t * HW;
    mzt[p0] = make_float2(M0, 1.f / Z0);
    mzt[p1] = make_float2(M1, 1.f / Z1);
    mzt[p2] = make_float2(M2, 1.f / Z2);
}

#define REP49(M) M(0)M(1)M(2)M(3)M(4)M(5)M(6)M(7)M(8)M(9)M(10)M(11)M(12)M(13) \
    M(14)M(15)M(16)M(17)M(18)M(19)M(20)M(21)M(22)M(23)M(24)M(25)M(26)M(27) \
    M(28)M(29)M(30)M(31)M(32)M(33)M(34)M(35)M(36)M(37)M(38)M(39)M(40)M(41) \
    M(42)M(43)M(44)M(45)M(46)M(47)M(48)

#define QOFF(k) (((k) / 7 - PD) * HLW + ((k) % 7 - PD))

// ================= fused: E (in-LDS) + MFMA attn + norm + linear =================
// 12x16 tile, 512 threads. SC=64 (8 planes/chunk), 5 chunks, dbuf. Wave owns tile
// rows r0,r0+1; A = output-row px (cols clamped; D rows i>=12 garbage, masked at
// write-out). __expf = native v_exp path. {M,iZ} packed float2 (1 load/halo px).

__launch_bounds__(512, 2)
__global__ void k_main(const float* __restrict__ x, const float* __restrict__ Wlin,
                       const float* __restrict__ blin, const float* __restrict__ ws,
                       float* __restrict__ out) {
    __shared__ __align__(16) char ebuf[2][8 * PSTRG * 16];   // 102400 B (attn overlay aliases)
    __shared__ float4 sfh[NHP];                       // xyz = feature, w = iZ (0 if OOB)
    __shared__ float  sW[441];
    __shared__ float4 smean[SP];                      // 5120 B

    const int tid = threadIdx.x;
    const int wid = tid >> 6, lane = tid & 63;
    const int pxc = lane & 15, kg = lane >> 4;        // MFMA fragment coords
    const int t = blockIdx.z;
    const int gx0 = blockIdx.x * TSW - PD, gy0 = blockIdx.y * TSH - PD;
    const float4* m4 = (const float4*)(ws + MEANS) + t * SP;

    for (int i = tid; i < 441; i += 512) sW[i] = Wlin[i];
    for (int i = tid; i < SP; i += 512) smean[i] = m4[i];

    // ---- per-halo-pixel state (loads only; M/iZ precomputed, packed) ----
    float fx = 0.f, fy = 0.f, fz = 0.f, M = INFINITY;
    if (tid < NHP) {
        int hy = tid / HLW, hx = tid - hy * HLW;
        int gy = gy0 + hy, gx = gx0 + hx;
        float iZ = 0.f;
        if (gy >= 0 && gy < HH && gx >= 0 && gx < WW) {
            int p = gy * WW + gx;
            fx = x[(t * 3 + 0) * HW + p];
            fy = x[(t * 3 + 1) * HW + p];
            fz = x[(t * 3 + 2) * HW + p];
            float2 mz = ((const float2*)(ws + MOFF))[t * HW + p];
            M  = mz.x;
            iZ = mz.y;
        }
        sfh[tid] = make_float4(fx, fy, fz, iZ);
    }
    __syncthreads();   // smean (and sfh/sW) visible before PHASEB(0)

    // phase B: E for chunk cc (64 s = 8 planes) -> buffer bb (OOB px: M=+inf -> E=0)
#define PHASEB(cc, bb) if (tid < NHP) { \
        char* dst = ebuf[bb]; \
        _Pragma("unroll") \
        for (int jd = 0; jd < 8; jd++) { \
            h8 v; \
            _Pragma("unroll") \
            for (int e = 0; e < 4; e++) { \
                float4 ma = smean[(cc) * 64 + jd * 8 + 2 * e]; \
                float4 mb = smean[(cc) * 64 + jd * 8 + 2 * e + 1]; \
                float E0 = __expf(fmaf(fx, ma.x, fmaf(fy, ma.y, fmaf(fz, ma.z, ma.w))) - M); \
                float E1 = __expf(fmaf(fx, mb.x, fmaf(fy, mb.y, fmaf(fz, mb.z, mb.w))) - M); \
                auto pr = __builtin_amdgcn_cvt_pkrtz(E0, E1); \
                v[2 * e] = (_Float16)pr.x; v[2 * e + 1] = (_Float16)pr.y; \
            } \
            *(h8*)(dst + (jd * PSTRG + tid) * 16) = v; \
        } }

    // ---- MFMA setup: wave owns tile rows r0, r0+1 ----
    const int r0 = 2 * wid;
    const int acol = (pxc > 14) ? 14 : pxc;                         // A col clamp (i>=12 masked)
    const int gA0 = kg * PSTRG + (r0 + PD) * HLW + PD + acol;       // A row r0
    const int gA1 = gA0 + HLW;                                      // A row r0+1
    const int bcol2 = (16 + pxc > 17) ? 17 : 16 + pxc;              // clamped tile2 col
    const int gB1 = kg * PSTRG + r0 * HLW + pxc;                    // + d*HLW
    const int gB2 = kg * PSTRG + r0 * HLW + bcol2;                  // + d*HLW

    f4 zero4 = {0.f, 0.f, 0.f, 0.f};
    f4 aP[7], aQ[7], aR[7], aS[7];   // (A0,B1[d]) (A0,B2[d]) (A1,B1[d+1]) (A1,B2[d+1])
#pragma unroll
    for (int d = 0; d < 7; d++) { aP[d] = zero4; aQ[d] = zero4; aR[d] = zero4; aS[d] = zero4; }

    // one K=32 step (4 planes at pbk), depth-1 B rotation prefetch
#define MFMA_STEP(pbk) { \
        h8 A0 = *(const h8*)((pbk) + gA0 * 16); \
        h8 A1 = *(const h8*)((pbk) + gA1 * 16); \
        h8 c1 = *(const h8*)((pbk) + gB1 * 16); \
        h8 c2 = *(const h8*)((pbk) + gB2 * 16); \
        h8 n1 = *(const h8*)((pbk) + (gB1 + HLW) * 16); \
        h8 n2 = *(const h8*)((pbk) + (gB2 + HLW) * 16); \
        aP[0] = __builtin_amdgcn_mfma_f32_16x16x32_f16(A0, c1, aP[0], 0, 0, 0); \
        aQ[0] = __builtin_amdgcn_mfma_f32_16x16x32_f16(A0, c2, aQ[0], 0, 0, 0); \
        _Pragma("unroll") \
        for (int d = 1; d < 7; d++) { \
            h8 f1 = *(const h8*)((pbk) + (gB1 + (d + 1) * HLW) * 16); \
            h8 f2 = *(const h8*)((pbk) + (gB2 + (d + 1) * HLW) * 16); \
            aP[d]     = __builtin_amdgcn_mfma_f32_16x16x32_f16(A0, n1, aP[d], 0, 0, 0); \
            aR[d - 1] = __builtin_amdgcn_mfma_f32_16x16x32_f16(A1, n1, aR[d - 1], 0, 0, 0); \
            aQ[d]     = __builtin_amdgcn_mfma_f32_16x16x32_f16(A0, n2, aQ[d], 0, 0, 0); \
            aS[d - 1] = __builtin_amdgcn_mfma_f32_16x16x32_f16(A1, n2, aS[d - 1], 0, 0, 0); \
            n1 = f1; n2 = f2; \
        } \
        aR[6] = __builtin_amdgcn_mfma_f32_16x16x32_f16(A1, n1, aR[6], 0, 0, 0); \
        aS[6] = __builtin_amdgcn_mfma_f32_16x16x32_f16(A1, n2, aS[6], 0, 0, 0); }

#define MFMA_CHUNK { \
        __builtin_amdgcn_s_setprio(1); \
        MFMA_STEP(pb) \
        MFMA_STEP(pb + 4 * PSTRG * 16) \
        __builtin_amdgcn_s_setprio(0); }

    PHASEB(0, 0)

#pragma unroll 1
    for (int c = 0; c < 5; c++) {
        __syncthreads();               // phaseB(c) visible; MFMA(c-1) reads done
        const char* pb = ebuf[c & 1];
        if (wid & 1) {                 // stagger: odd waves MFMA first
            MFMA_CHUNK
            if (c < 4) { PHASEB(c + 1, (c + 1) & 1) }
        } else {
            if (c < 4) { PHASEB(c + 1, (c + 1) & 1) }
            MFMA_CHUNK
        }
    }
    __syncthreads();                   // last MFMA reads done; ebuf reusable

    // ---- band write-out: D[i,j] -> attn[px][k]; rows i>=12 are garbage (masked) ----
    float* attn = (float*)ebuf;        // [192 px][stride 51] f32, 39.2 KB
#pragma unroll
    for (int d = 0; d < 7; d++) {
#pragma unroll
        for (int reg = 0; reg < 4; reg++) {
            int i = 4 * kg + reg;
            int u1 = pxc - i;          // tile1: dx+3 = j-i
            int u2 = u1 + 16;          // tile2: dx+3 = 16+j-i
            if (i < TSW) {
                if ((unsigned)u1 <= 6u) {
                    attn[(r0 * TSW + i) * 51 + d * 7 + u1] = aP[d][reg];
                    attn[((r0 + 1) * TSW + i) * 51 + d * 7 + u1] = aR[d][reg];
                }
                if ((unsigned)u2 <= 6u) {
                    attn[(r0 * TSW + i) * 51 + d * 7 + u2] = aQ[d][reg];
                    attn[((r0 + 1) * TSW + i) * 51 + d * 7 + u2] = aS[d][reg];
                }
            }
        }
    }
    __syncthreads();

    // ---- normalize (eps+max semantics) + linear epilogue (1 thread / pixel) ----
    if (tid < TSH * TSW) {
        const int r = tid / TSW, cq = tid - r * TSW;
        const int own = (r + PD) * HLW + (cq + PD);
        const float* ap = attn + tid * 51;
        float mx = 0.f;
#define PK1(k) mx = fmaxf(mx, ap[k] * sfh[own + QOFF(k)].w);
        REP49(PK1)
#undef PK1
        const float iZp = sfh[own].w;
        const float inv = 1.f / (1e-5f / iZp + mx);

        float o0 = blin[0], o1 = blin[1], o2 = blin[2];
#define PK2(k) { float4 f = sfh[own + QOFF(k)]; \
        float rwk = ap[k] * f.w * inv; \
        o0 += rwk * (sW[k] * f.x + sW[49 + (k)] * f.y + sW[98 + (k)] * f.z); \
        o1 += rwk * (sW[147 + (k)] * f.x + sW[196 + (k)] * f.y + sW[245 + (k)] * f.z); \
        o2 += rwk * (sW[294 + (k)] * f.x + sW[343 + (k)] * f.y + sW[392 + (k)] * f.z); }
        REP49(PK2)
#undef PK2

        int p = (gy0 + PD + r) * WW + gx0 + PD + cq;
        out[(t * 3 + 0) * HW + p] = o0;
        out[(t * 3 + 1) * HW + p] = o1;
        out[(t * 3 + 2) * HW + p] = o2;
    }
}

extern "C" void kernel_launch(void* const* d_in, const int* in_sizes, int n_in,
                              void* d_out, int out_size, void* d_ws, size_t ws_size,
                              hipStream_t stream) {
    (void)in_sizes; (void)n_in; (void)out_size; (void)ws_size;
    const float* x    = (const float*)d_in[0];
    const int*   spix = (const int*)d_in[1];
    const float* Wlin = (const float*)d_in[2];
    const float* blin = (const float*)d_in[3];
    float* out = (float*)d_out;
    float* ws  = (float*)d_ws;

    hipLaunchKernelGGL(k_accum, dim3(NSEG, TT), dim3(256), 0, stream, x, spix, ws);
    hipLaunchKernelGGL(k_prep,  dim3(HW / 768, TT), dim3(256), 0, stream, x, ws);
    hipLaunchKernelGGL(k_main,  dim3(WW / TSW, HH / TSH, TT), dim3(512), 0, stream,
                       x, Wlin, blin, ws, out);
}